// Round 12
// baseline (899.775 us; speedup 1.0000x reference)
//
#include <hip/hip_runtime.h>
#include <hip/hip_bf16.h>
#include <math.h>

typedef __attribute__((ext_vector_type(8))) short bf16x8;
typedef __attribute__((ext_vector_type(4))) float f32x4;
typedef unsigned short ushort_t;

constexpr float F_CUTOFF = 10.0f;
constexpr float F_EPS_W  = 1e-5f;
constexpr float F_EPS_LN = 1e-5f;
constexpr float F_PI     = 3.14159265358979323846f;

__device__ __forceinline__ float silu_f(float v)   { return v / (1.0f + __expf(-v)); }
__device__ __forceinline__ float sigmoid_f(float v){ return 1.0f / (1.0f + __expf(-v)); }

__device__ __forceinline__ ushort_t f2bf(float f) {
    union { __hip_bfloat16 h; ushort_t u; } v; v.h = __float2bfloat16(f); return v.u;
}
__device__ __forceinline__ float bf2f(ushort_t u) {
    union { unsigned u; float f; } v; v.u = ((unsigned)u) << 16; return v.f;
}

// ---------------------------------------------------------------------------
// CSR build (parallel scan) — proven R8
// ---------------------------------------------------------------------------
__global__ void count_kernel(const int* __restrict__ eidx, int* __restrict__ cnt, int E)
{
    int e = blockIdx.x * 256 + threadIdx.x;
    if (e < E) atomicAdd(&cnt[eidx[e]], 1);
}

__global__ __launch_bounds__(256)
void scan_sum_kernel(const int* __restrict__ cnt, int* __restrict__ part, int N, int range)
{
    __shared__ int red[256];
    int base = blockIdx.x * range;
    int s = 0;
    for (int i = threadIdx.x; i < range; i += 256) {
        int idx = base + i;
        if (idx < N) s += cnt[idx];
    }
    red[threadIdx.x] = s;
    __syncthreads();
    #pragma unroll
    for (int o = 128; o > 0; o >>= 1) {
        if (threadIdx.x < o) red[threadIdx.x] += red[threadIdx.x + o];
        __syncthreads();
    }
    if (threadIdx.x == 0) part[blockIdx.x] = red[0];
}

__global__ __launch_bounds__(256)
void scan_write_kernel(const int* __restrict__ part, int* __restrict__ cnt /*->cursor*/,
                       int* __restrict__ start, int N, int range, int E)
{
    __shared__ int ex[256];
    int tid = threadIdx.x;
    int v = part[tid];
    ex[tid] = v;
    __syncthreads();
    for (int o = 1; o < 256; o <<= 1) {
        int add = (tid >= o) ? ex[tid - o] : 0;
        __syncthreads();
        ex[tid] += add;
        __syncthreads();
    }
    int run = ex[tid] - v;
    int base = tid * range;
    for (int i = 0; i < range; ++i) {
        int idx = base + i;
        if (idx < N) {
            int c = cnt[idx];
            start[idx] = run;
            cnt[idx] = run;
            run += c;
        }
    }
    if (tid == 0) start[N] = E;
}

__global__ void scatter_kernel(const int* __restrict__ eidx, const float* __restrict__ dist,
                               int* __restrict__ cursor,
                               int* __restrict__ colp, int* __restrict__ nodep,
                               float* __restrict__ distp, int E)
{
    int e = blockIdx.x * 256 + threadIdx.x;
    if (e < E) {
        int row = eidx[e];
        int s = atomicAdd(&cursor[row], 1);
        colp[s]  = eidx[E + e];
        nodep[s] = row;
        distp[s] = dist[e];
    }
}

// ---------------------------------------------------------------------------
// Weight prep / casts
// ---------------------------------------------------------------------------
__global__ void cvt_transpose_kernel(const float* __restrict__ in, ushort_t* __restrict__ out,
                                     int K, int N, int logK)
{
    int idx = blockIdx.x * 256 + threadIdx.x;
    if (idx >= K * N) return;
    int n = idx >> logK;
    int k = idx & (K - 1);
    out[idx] = f2bf(in[k * N + n]);
}

__global__ void combine_w_kernel(const float* __restrict__ w2, const float* __restrict__ fw1,
                                 ushort_t* __restrict__ out)
{
    int idx = blockIdx.x * 256 + threadIdx.x;
    int c = idx >> 6, j = idx & 63;
    float s = 0.f;
    #pragma unroll 8
    for (int n = 0; n < 64; ++n) s += w2[j * 64 + n] * fw1[n * 256 + c];
    out[idx] = f2bf(s);
}

__global__ void combine_b_kernel(const float* __restrict__ b2, const float* __restrict__ fw1,
                                 const float* __restrict__ fb1, float* __restrict__ out)
{
    int c = threadIdx.x;
    float s = fb1[c];
    #pragma unroll 8
    for (int n = 0; n < 64; ++n) s += b2[n] * fw1[n * 256 + c];
    out[c] = s;
}

// f32 -> bf16 streaming cast (4 elems/thread)
__global__ __launch_bounds__(256)
void cast_bf16_kernel(const float* __restrict__ in, ushort_t* __restrict__ out, long n4)
{
    long i = (long)blockIdx.x * 256 + threadIdx.x;
    if (i >= n4) return;
    float4 v = reinterpret_cast<const float4*>(in)[i];
    ushort_t o[4] = {f2bf(v.x), f2bf(v.y), f2bf(v.z), f2bf(v.w)};
    *reinterpret_cast<uint2*>(out + i * 4) = *reinterpret_cast<uint2*>(o);
}

// ---------------------------------------------------------------------------
// Fallback y-GEMM (fp32 VALU): y = x @ node_w + node_b (bf16 out)
// ---------------------------------------------------------------------------
__global__ __launch_bounds__(256)
void gemm256_bf16_kernel(const float* __restrict__ A, const float* __restrict__ Wm,
                         const float* __restrict__ bias, ushort_t* __restrict__ out, int M)
{
    __shared__ float4 As4[64][64];
    const int t = threadIdx.x;
    const int row0 = blockIdx.x * 64;

    #pragma unroll
    for (int i = 0; i < 16; ++i) {
        int flat = t + i * 256;
        int r = flat >> 6, k4 = flat & 63;
        int row = row0 + r;
        float4 v = make_float4(0.f, 0.f, 0.f, 0.f);
        if (row < M) v = reinterpret_cast<const float4*>(A)[row * 64 + k4];
        As4[r][k4] = v;
    }
    __syncthreads();

    const int jt  = t & 31;
    const int et  = t >> 5;
    const int j04 = jt * 2;
    const int r0  = et * 8;

    float acc[8][8];
    #pragma unroll
    for (int r = 0; r < 8; ++r)
        #pragma unroll
        for (int c = 0; c < 8; ++c) acc[r][c] = 0.f;

    for (int k4 = 0; k4 < 64; ++k4) {
        float4 a4[8];
        #pragma unroll
        for (int r = 0; r < 8; ++r) a4[r] = As4[r0 + r][k4];
        #pragma unroll
        for (int q = 0; q < 4; ++q) {
            const int k = k4 * 4 + q;
            float4 b0 = reinterpret_cast<const float4*>(Wm)[k * 64 + j04];
            float4 b1 = reinterpret_cast<const float4*>(Wm)[k * 64 + j04 + 1];
            float bb[8] = {b0.x, b0.y, b0.z, b0.w, b1.x, b1.y, b1.z, b1.w};
            float av;
            #pragma unroll
            for (int r = 0; r < 8; ++r) {
                av = (q == 0) ? a4[r].x : (q == 1) ? a4[r].y : (q == 2) ? a4[r].z : a4[r].w;
                #pragma unroll
                for (int c = 0; c < 8; ++c) acc[r][c] = fmaf(av, bb[c], acc[r][c]);
            }
        }
    }

    float4 bv0 = reinterpret_cast<const float4*>(bias)[j04];
    float4 bv1 = reinterpret_cast<const float4*>(bias)[j04 + 1];
    float bb[8] = {bv0.x, bv0.y, bv0.z, bv0.w, bv1.x, bv1.y, bv1.z, bv1.w};

    #pragma unroll
    for (int r = 0; r < 8; ++r) {
        int row = row0 + r0 + r;
        if (row >= M) continue;
        ushort_t o8[8];
        #pragma unroll
        for (int c = 0; c < 8; ++c) o8[c] = f2bf(acc[r][c] + bb[c]);
        *reinterpret_cast<uint4*>(out + (size_t)row * 256 + jt * 8) = *reinterpret_cast<uint4*>(o8);
    }
}

// ---------------------------------------------------------------------------
// Fallback gate GEMM (fp32 VALU)
// ---------------------------------------------------------------------------
__global__ __launch_bounds__(256)
void gate_gemm_kernel(const float* __restrict__ A, const float* __restrict__ Wm,
                      const float* __restrict__ bias, float* __restrict__ out, int M)
{
    __shared__ float4 As4[64][64];
    const int t = threadIdx.x;
    const int row0 = blockIdx.x * 64;

    #pragma unroll
    for (int i = 0; i < 16; ++i) {
        int flat = t + i * 256;
        int r = flat >> 6, k4 = flat & 63;
        int row = row0 + r;
        float4 v = make_float4(0.f, 0.f, 0.f, 0.f);
        if (row < M) v = reinterpret_cast<const float4*>(A)[row * 64 + k4];
        As4[r][k4] = v;
    }
    __syncthreads();

    const int jt  = t & 31;
    const int et  = t >> 5;
    const int j04 = jt * 2;
    const int r0  = et * 8;

    float acc[8][8];
    #pragma unroll
    for (int r = 0; r < 8; ++r)
        #pragma unroll
        for (int c = 0; c < 8; ++c) acc[r][c] = 0.f;

    for (int k4 = 0; k4 < 64; ++k4) {
        float4 a4[8];
        #pragma unroll
        for (int r = 0; r < 8; ++r) a4[r] = As4[r0 + r][k4];
        #pragma unroll
        for (int q = 0; q < 4; ++q) {
            const int k = k4 * 4 + q;
            float4 b0 = reinterpret_cast<const float4*>(Wm)[k * 64 + j04];
            float4 b1 = reinterpret_cast<const float4*>(Wm)[k * 64 + j04 + 1];
            float bb[8] = {b0.x, b0.y, b0.z, b0.w, b1.x, b1.y, b1.z, b1.w};
            float av;
            #pragma unroll
            for (int r = 0; r < 8; ++r) {
                av = (q == 0) ? a4[r].x : (q == 1) ? a4[r].y : (q == 2) ? a4[r].z : a4[r].w;
                #pragma unroll
                for (int c = 0; c < 8; ++c) acc[r][c] = fmaf(av, bb[c], acc[r][c]);
            }
        }
    }

    float4 bv0 = reinterpret_cast<const float4*>(bias)[j04];
    float4 bv1 = reinterpret_cast<const float4*>(bias)[j04 + 1];
    float bb[8] = {bv0.x, bv0.y, bv0.z, bv0.w, bv1.x, bv1.y, bv1.z, bv1.w};

    #pragma unroll
    for (int r = 0; r < 8; ++r) {
        int row = row0 + r0 + r;
        if (row >= M) continue;
        float4 a0 = As4[r0 + r][j04];
        float4 a1 = As4[r0 + r][j04 + 1];
        float aa[8] = {a0.x, a0.y, a0.z, a0.w, a1.x, a1.y, a1.z, a1.w};
        float o[8];
        #pragma unroll
        for (int c = 0; c < 8; ++c) o[c] = aa[c] * sigmoid_f(acc[r][c] + bb[c]);
        reinterpret_cast<float4*>(out)[row * 64 + j04]     = make_float4(o[0], o[1], o[2], o[3]);
        reinterpret_cast<float4*>(out)[row * 64 + j04 + 1] = make_float4(o[4], o[5], o[6], o[7]);
    }
}

// ---------------------------------------------------------------------------
// A+B fused: t1[Mc,64] = silu(rbf(dist) @ wt1 + b1).  RBF computed directly
// into the LDS staging tile (no r round-trip).  K=64, N=64, BM=128.
// ---------------------------------------------------------------------------
__global__ __launch_bounds__(256, 4)
void rbf_t1_kernel(const float* __restrict__ distp,
                   const float* __restrict__ centers, const float* __restrict__ widths,
                   const ushort_t* __restrict__ Wt, const float* __restrict__ bias,
                   ushort_t* __restrict__ out, int M)
{
    __shared__ __align__(16) unsigned char sA[128 * 128];   // 16 KB; reused as out-bounce
    const int t = threadIdx.x;
    const int m0 = blockIdx.x * 128;
    const int w = t >> 6, lane = t & 63;
    const int g = lane >> 4, q = lane & 15;

    #pragma unroll
    for (int i = 0; i < 4; ++i) {
        int s = t + i * 256;
        int r = s >> 3, u = s & 7;
        int row = m0 + r;
        float d = (row < M) ? distp[row] : F_CUTOFF;
        float env = (d < F_CUTOFF) ? 0.5f * (__cosf(d * (F_PI / F_CUTOFF)) + 1.0f) : 0.0f;
        int c0 = (u ^ (r & 7)) * 8;
        ushort_t o[8];
        #pragma unroll
        for (int j = 0; j < 8; ++j) {
            int n = c0 + j;
            float wd = fabsf(widths[n]) + F_EPS_W;
            float z = (d - centers[n]) / wd;
            o[j] = f2bf(env * __expf(-0.5f * z * z));
        }
        *reinterpret_cast<uint4*>(sA + s * 16) = *reinterpret_cast<uint4*>(o);
    }
    __syncthreads();

    f32x4 acc[2][4];
    #pragma unroll
    for (int mt = 0; mt < 2; ++mt)
        #pragma unroll
        for (int nt = 0; nt < 4; ++nt) acc[mt][nt] = (f32x4){0.f, 0.f, 0.f, 0.f};

    #pragma unroll
    for (int kk = 0; kk < 2; ++kk) {
        bf16x8 b[4];
        #pragma unroll
        for (int nt = 0; nt < 4; ++nt) {
            int n = nt * 16 + q;
            b[nt] = *reinterpret_cast<const bf16x8*>(Wt + n * 64 + kk * 32 + g * 8);
        }
        bf16x8 a[2];
        #pragma unroll
        for (int mt = 0; mt < 2; ++mt) {
            int m = w * 32 + mt * 16 + q;
            int unit = (4 * kk + g) ^ (m & 7);
            a[mt] = *reinterpret_cast<const bf16x8*>(sA + m * 128 + unit * 16);
        }
        #pragma unroll
        for (int mt = 0; mt < 2; ++mt)
            #pragma unroll
            for (int nt = 0; nt < 4; ++nt)
                acc[mt][nt] = __builtin_amdgcn_mfma_f32_16x16x32_bf16(a[mt], b[nt], acc[mt][nt], 0, 0, 0);
    }
    __syncthreads();   // all sA reads done -> reuse as out-bounce

    const bool evenq = (q & 1) == 0;
    #pragma unroll
    for (int nt = 0; nt < 4; ++nt) {
        int n0  = nt * 16 + q;
        int n_e = n0 & ~1;
        float2 bv = *reinterpret_cast<const float2*>(bias + n_e);
        #pragma unroll
        for (int mt = 0; mt < 2; ++mt) {
            float v[4], p[4];
            #pragma unroll
            for (int r = 0; r < 4; ++r) { v[r] = acc[mt][nt][r]; p[r] = __shfl_xor(v[r], 1, 64); }
            #pragma unroll
            for (int rr = 0; rr < 2; ++rr) {
                int r = evenq ? rr : (2 + rr);
                float lo = silu_f((evenq ? v[r] : p[r]) + bv.x);
                float hi = silu_f((evenq ? p[r] : v[r]) + bv.y);
                int m = w * 32 + mt * 16 + 4 * g + r;
                unsigned u = (unsigned)f2bf(lo) | ((unsigned)f2bf(hi) << 16);
                *reinterpret_cast<unsigned*>(sA + m * 128 + n_e * 2) = u;
            }
        }
    }
    __syncthreads();

    {
        int row = t >> 1, j = t & 1;
        if (m0 + row < M) {
            #pragma unroll
            for (int i = 0; i < 4; ++i) {
                uint4 v = *reinterpret_cast<const uint4*>(sA + row * 128 + (j * 4 + i) * 16);
                *reinterpret_cast<uint4*>(out + (size_t)(m0 + row) * 64 + (j * 4 + i) * 8) = v;
            }
        }
    }
}

// ---------------------------------------------------------------------------
// C: f1[Mc,256] = silu(t1 @ wcomb + bcomb).  K=64, N=256, BM=64.
// ---------------------------------------------------------------------------
__global__ __launch_bounds__(256, 4)
void gemm_k64n256_kernel(const ushort_t* __restrict__ A, const ushort_t* __restrict__ Wt,
                         const float* __restrict__ bias, ushort_t* __restrict__ out, int M)
{
    __shared__ __align__(16) unsigned char sA[64 * 128];
    __shared__ __align__(16) unsigned char obuf[32 * 512];
    const int t = threadIdx.x;
    const int m0 = blockIdx.x * 64;
    const int wn = t >> 6, lane = t & 63;
    const int g = lane >> 4, q = lane & 15;

    #pragma unroll
    for (int i = 0; i < 2; ++i) {
        int s = t + i * 256;
        int r = s >> 3, u = s & 7;
        int row = m0 + r; row = (row < M) ? row : (M - 1);
        uint4 v = *reinterpret_cast<const uint4*>(A + (size_t)row * 64 + ((u ^ (r & 7)) * 8));
        *reinterpret_cast<uint4*>(sA + s * 16) = v;
    }
    __syncthreads();

    f32x4 acc[4][4];
    #pragma unroll
    for (int mt = 0; mt < 4; ++mt)
        #pragma unroll
        for (int nt = 0; nt < 4; ++nt) acc[mt][nt] = (f32x4){0.f, 0.f, 0.f, 0.f};

    #pragma unroll
    for (int kk = 0; kk < 2; ++kk) {
        bf16x8 b[4];
        #pragma unroll
        for (int nt = 0; nt < 4; ++nt) {
            int n = wn * 64 + nt * 16 + q;
            b[nt] = *reinterpret_cast<const bf16x8*>(Wt + n * 64 + kk * 32 + g * 8);
        }
        bf16x8 a[4];
        #pragma unroll
        for (int mt = 0; mt < 4; ++mt) {
            int m = mt * 16 + q;
            int unit = (4 * kk + g) ^ (m & 7);
            a[mt] = *reinterpret_cast<const bf16x8*>(sA + m * 128 + unit * 16);
        }
        #pragma unroll
        for (int mt = 0; mt < 4; ++mt)
            #pragma unroll
            for (int nt = 0; nt < 4; ++nt)
                acc[mt][nt] = __builtin_amdgcn_mfma_f32_16x16x32_bf16(a[mt], b[nt], acc[mt][nt], 0, 0, 0);
    }

    const bool evenq = (q & 1) == 0;
    #pragma unroll
    for (int half = 0; half < 2; ++half) {
        #pragma unroll
        for (int mtl = 0; mtl < 2; ++mtl) {
            int mt = half * 2 + mtl;
            #pragma unroll
            for (int nt = 0; nt < 4; ++nt) {
                int n0  = wn * 64 + nt * 16 + q;
                int n_e = n0 & ~1;
                float2 bv = *reinterpret_cast<const float2*>(bias + n_e);
                float v[4], p[4];
                #pragma unroll
                for (int r = 0; r < 4; ++r) { v[r] = acc[mt][nt][r]; p[r] = __shfl_xor(v[r], 1, 64); }
                #pragma unroll
                for (int rr = 0; rr < 2; ++rr) {
                    int r = evenq ? rr : (2 + rr);
                    float lo = silu_f((evenq ? v[r] : p[r]) + bv.x);
                    float hi = silu_f((evenq ? p[r] : v[r]) + bv.y);
                    int ml = mtl * 16 + 4 * g + r;
                    unsigned u = (unsigned)f2bf(lo) | ((unsigned)f2bf(hi) << 16);
                    *reinterpret_cast<unsigned*>(obuf + ml * 512 + n_e * 2) = u;
                }
            }
        }
        __syncthreads();
        {
            int row = t >> 3, c = t & 7;
            int grow = m0 + half * 32 + row;
            if (grow < M) {
                #pragma unroll
                for (int i = 0; i < 4; ++i) {
                    uint4 v = *reinterpret_cast<const uint4*>(obuf + row * 512 + (c + 8 * i) * 16);
                    *reinterpret_cast<uint4*>(out + (size_t)grow * 256 + (c + 8 * i) * 8) = v;
                }
            }
        }
        __syncthreads();
    }
}

// ---------------------------------------------------------------------------
// gemm_k256<SILU>: out[M,256] = act(A[M,256] @ W + bias), bf16 in/out.
// BM=64, BK=64 dbuf LDS, coalesced bounce store.  (R9/R10 proven)
// ---------------------------------------------------------------------------
template<bool SILU>
__global__ __launch_bounds__(256, 4)
void gemm_k256_kernel(const ushort_t* __restrict__ A, const ushort_t* __restrict__ Wt,
                      const float* __restrict__ bias, ushort_t* __restrict__ out, int M)
{
    __shared__ __align__(16) unsigned char sbuf[2][8192];

    const int t  = threadIdx.x;
    const int m0 = blockIdx.x * 64;
    const int wn   = t >> 6;
    const int lane = t & 63;
    const int g = lane >> 4, q = lane & 15;

    const int s0r = t >> 3,         s0u = t & 7;
    const int s1r = (t + 256) >> 3, s1u = t & 7;
    const ushort_t* src0base = A + (size_t)((m0 + s0r < M) ? (m0 + s0r) : (M - 1)) * 256 + ((s0u ^ (s0r & 7)) * 8);
    const ushort_t* src1base = A + (size_t)((m0 + s1r < M) ? (m0 + s1r) : (M - 1)) * 256 + ((s1u ^ (s1r & 7)) * 8);

    uint4 p0 = *reinterpret_cast<const uint4*>(src0base);
    uint4 p1 = *reinterpret_cast<const uint4*>(src1base);
    *reinterpret_cast<uint4*>(&sbuf[0][t * 16])         = p0;
    *reinterpret_cast<uint4*>(&sbuf[0][(t + 256) * 16]) = p1;
    __syncthreads();

    f32x4 acc[4][4];
    #pragma unroll
    for (int mt = 0; mt < 4; ++mt)
        #pragma unroll
        for (int nt = 0; nt < 4; ++nt) acc[mt][nt] = (f32x4){0.f, 0.f, 0.f, 0.f};

    for (int kt = 0; kt < 4; ++kt) {
        const int cur = kt & 1;
        uint4 nx0, nx1;
        if (kt < 3) {
            nx0 = *reinterpret_cast<const uint4*>(src0base + (kt + 1) * 64);
            nx1 = *reinterpret_cast<const uint4*>(src1base + (kt + 1) * 64);
        }
        #pragma unroll
        for (int ks = 0; ks < 2; ++ks) {
            bf16x8 b[4];
            #pragma unroll
            for (int nt = 0; nt < 4; ++nt) {
                int n = wn * 64 + nt * 16 + q;
                b[nt] = *reinterpret_cast<const bf16x8*>(Wt + (size_t)n * 256 + kt * 64 + ks * 32 + g * 8);
            }
            bf16x8 a[4];
            #pragma unroll
            for (int mt = 0; mt < 4; ++mt) {
                int r = mt * 16 + q;
                int u = (ks * 4 + g) ^ (r & 7);
                a[mt] = *reinterpret_cast<const bf16x8*>(&sbuf[cur][r * 128 + u * 16]);
            }
            #pragma unroll
            for (int mt = 0; mt < 4; ++mt)
                #pragma unroll
                for (int nt = 0; nt < 4; ++nt)
                    acc[mt][nt] = __builtin_amdgcn_mfma_f32_16x16x32_bf16(a[mt], b[nt], acc[mt][nt], 0, 0, 0);
        }
        __syncthreads();
        if (kt < 3) {
            *reinterpret_cast<uint4*>(&sbuf[cur ^ 1][t * 16])         = nx0;
            *reinterpret_cast<uint4*>(&sbuf[cur ^ 1][(t + 256) * 16]) = nx1;
            __syncthreads();
        }
    }

    // bounce epilogue via sbuf (32 rows x 512B), 2 half-passes
    unsigned char* obuf = &sbuf[0][0];
    const bool evenq = (q & 1) == 0;
    #pragma unroll
    for (int half = 0; half < 2; ++half) {
        __syncthreads();
        #pragma unroll
        for (int mtl = 0; mtl < 2; ++mtl) {
            int mt = half * 2 + mtl;
            #pragma unroll
            for (int nt = 0; nt < 4; ++nt) {
                int n0  = wn * 64 + nt * 16 + q;
                int n_e = n0 & ~1;
                float2 bv = *reinterpret_cast<const float2*>(bias + n_e);
                float v[4], p[4];
                #pragma unroll
                for (int r = 0; r < 4; ++r) { v[r] = acc[mt][nt][r]; p[r] = __shfl_xor(v[r], 1, 64); }
                #pragma unroll
                for (int rr = 0; rr < 2; ++rr) {
                    int r = evenq ? rr : (2 + rr);
                    float lo = (evenq ? v[r] : p[r]) + bv.x;
                    float hi = (evenq ? p[r] : v[r]) + bv.y;
                    if (SILU) { lo = silu_f(lo); hi = silu_f(hi); }
                    int ml = mtl * 16 + 4 * g + r;
                    unsigned u = (unsigned)f2bf(lo) | ((unsigned)f2bf(hi) << 16);
                    *reinterpret_cast<unsigned*>(obuf + ml * 512 + n_e * 2) = u;
                }
            }
        }
        __syncthreads();
        {
            int row = t >> 3, c = t & 7;
            int grow = m0 + half * 32 + row;
            if (grow < M) {
                #pragma unroll
                for (int i = 0; i < 4; ++i) {
                    uint4 v = *reinterpret_cast<const uint4*>(obuf + row * 512 + (c + 8 * i) * 16);
                    *reinterpret_cast<uint4*>(out + (size_t)grow * 256 + (c + 8 * i) * 8) = v;
                }
            }
        }
    }
}

// ---------------------------------------------------------------------------
// Gate MFMA: d_out = d_out * sigmoid(a_bf @ gate_w + gb).  (R11 proven)
// ---------------------------------------------------------------------------
__global__ __launch_bounds__(256, 4)
void gate_mfma_kernel(const ushort_t* __restrict__ A, const ushort_t* __restrict__ Wt,
                      const float* __restrict__ bias, float* __restrict__ out, int M)
{
    __shared__ __align__(16) unsigned char sbuf[2][8192];
    __shared__ float obuf[16][260];

    const int t  = threadIdx.x;
    const int m0 = blockIdx.x * 64;
    const int wn   = t >> 6;
    const int lane = t & 63;
    const int g = lane >> 4, q = lane & 15;

    const int s0r = t >> 3,         s0u = t & 7;
    const int s1r = (t + 256) >> 3, s1u = t & 7;
    const ushort_t* src0base = A + (size_t)((m0 + s0r < M) ? (m0 + s0r) : (M - 1)) * 256 + ((s0u ^ (s0r & 7)) * 8);
    const ushort_t* src1base = A + (size_t)((m0 + s1r < M) ? (m0 + s1r) : (M - 1)) * 256 + ((s1u ^ (s1r & 7)) * 8);

    uint4 p0 = *reinterpret_cast<const uint4*>(src0base);
    uint4 p1 = *reinterpret_cast<const uint4*>(src1base);
    *reinterpret_cast<uint4*>(&sbuf[0][t * 16])         = p0;
    *reinterpret_cast<uint4*>(&sbuf[0][(t + 256) * 16]) = p1;
    __syncthreads();

    f32x4 acc[4][4];
    #pragma unroll
    for (int mt = 0; mt < 4; ++mt)
        #pragma unroll
        for (int nt = 0; nt < 4; ++nt) acc[mt][nt] = (f32x4){0.f, 0.f, 0.f, 0.f};

    for (int kt = 0; kt < 4; ++kt) {
        const int cur = kt & 1;
        uint4 nx0, nx1;
        if (kt < 3) {
            nx0 = *reinterpret_cast<const uint4*>(src0base + (kt + 1) * 64);
            nx1 = *reinterpret_cast<const uint4*>(src1base + (kt + 1) * 64);
        }
        #pragma unroll
        for (int ks = 0; ks < 2; ++ks) {
            bf16x8 b[4];
            #pragma unroll
            for (int nt = 0; nt < 4; ++nt) {
                int n = wn * 64 + nt * 16 + q;
                b[nt] = *reinterpret_cast<const bf16x8*>(Wt + (size_t)n * 256 + kt * 64 + ks * 32 + g * 8);
            }
            bf16x8 a[4];
            #pragma unroll
            for (int mt = 0; mt < 4; ++mt) {
                int r = mt * 16 + q;
                int u = (ks * 4 + g) ^ (r & 7);
                a[mt] = *reinterpret_cast<const bf16x8*>(&sbuf[cur][r * 128 + u * 16]);
            }
            #pragma unroll
            for (int mt = 0; mt < 4; ++mt)
                #pragma unroll
                for (int nt = 0; nt < 4; ++nt)
                    acc[mt][nt] = __builtin_amdgcn_mfma_f32_16x16x32_bf16(a[mt], b[nt], acc[mt][nt], 0, 0, 0);
        }
        __syncthreads();
        if (kt < 3) {
            *reinterpret_cast<uint4*>(&sbuf[cur ^ 1][t * 16])         = nx0;
            *reinterpret_cast<uint4*>(&sbuf[cur ^ 1][(t + 256) * 16]) = nx1;
            __syncthreads();
        }
    }

    float bn[4];
    #pragma unroll
    for (int nt = 0; nt < 4; ++nt) bn[nt] = bias[wn * 64 + nt * 16 + q];

    #pragma unroll
    for (int p = 0; p < 4; ++p) {
        #pragma unroll
        for (int nt = 0; nt < 4; ++nt) {
            int col = wn * 64 + nt * 16 + q;
            #pragma unroll
            for (int r = 0; r < 4; ++r) {
                int rl = 4 * g + r;
                obuf[rl][col] = sigmoid_f(acc[p][nt][r] + bn[nt]);
            }
        }
        __syncthreads();
        {
            int rl = t >> 4, c16 = t & 15;
            int grow = m0 + p * 16 + rl;
            if (grow < M) {
                float* orow = out + (size_t)grow * 256 + c16 * 16;
                #pragma unroll
                for (int i = 0; i < 4; ++i) {
                    float4 g4 = *reinterpret_cast<const float4*>(&obuf[rl][c16 * 16 + i * 4]);
                    float4 a4 = *reinterpret_cast<const float4*>(orow + i * 4);
                    a4.x *= g4.x; a4.y *= g4.y; a4.z *= g4.z; a4.w *= g4.w;
                    *reinterpret_cast<float4*>(orow + i * 4) = a4;
                }
            }
        }
        __syncthreads();
    }
}

// ---------------------------------------------------------------------------
// D+E fused: Wf[Mc,256] = (silu(A @ wf2 + b2)) @ wf3 + b3.
// Single-buffer staging (8 KB) + 32 KB f2l = 40 KB LDS -> 4 blocks/CU.
// In-place A->out safe (all A reads staged before first write).
// ---------------------------------------------------------------------------
__global__ __launch_bounds__(256, 4)
void fused_de_kernel(const ushort_t* A, const ushort_t* __restrict__ Wt2,
                     const float* __restrict__ b2,
                     const ushort_t* __restrict__ Wt3, const float* __restrict__ b3,
                     ushort_t* out, int M)
{
    __shared__ __align__(16) unsigned char sbuf[8192];      // staging (single) / obuf
    __shared__ __align__(16) unsigned char f2l[64 * 512];   // 32 KB f2 tile (swizzled)

    const int t  = threadIdx.x;
    const int m0 = blockIdx.x * 64;
    const int wn   = t >> 6;
    const int lane = t & 63;
    const int g = lane >> 4, q = lane & 15;

    const int s0r = t >> 3,         s0u = t & 7;
    const int s1r = (t + 256) >> 3, s1u = t & 7;
    const ushort_t* src0base = A + (size_t)((m0 + s0r < M) ? (m0 + s0r) : (M - 1)) * 256 + ((s0u ^ (s0r & 7)) * 8);
    const ushort_t* src1base = A + (size_t)((m0 + s1r < M) ? (m0 + s1r) : (M - 1)) * 256 + ((s1u ^ (s1r & 7)) * 8);

    uint4 p0 = *reinterpret_cast<const uint4*>(src0base);
    uint4 p1 = *reinterpret_cast<const uint4*>(src1base);
    *reinterpret_cast<uint4*>(&sbuf[t * 16])         = p0;
    *reinterpret_cast<uint4*>(&sbuf[(t + 256) * 16]) = p1;
    __syncthreads();

    f32x4 acc[4][4];
    #pragma unroll
    for (int mt = 0; mt < 4; ++mt)
        #pragma unroll
        for (int nt = 0; nt < 4; ++nt) acc[mt][nt] = (f32x4){0.f, 0.f, 0.f, 0.f};

    // ---- D: f2 = silu(A @ wf2 + b2), K=256, single-buffer staging
    for (int kt = 0; kt < 4; ++kt) {
        uint4 nx0, nx1;
        if (kt < 3) {
            nx0 = *reinterpret_cast<const uint4*>(src0base + (kt + 1) * 64);
            nx1 = *reinterpret_cast<const uint4*>(src1base + (kt + 1) * 64);
        }
        #pragma unroll
        for (int ks = 0; ks < 2; ++ks) {
            bf16x8 b[4];
            #pragma unroll
            for (int nt = 0; nt < 4; ++nt) {
                int n = wn * 64 + nt * 16 + q;
                b[nt] = *reinterpret_cast<const bf16x8*>(Wt2 + (size_t)n * 256 + kt * 64 + ks * 32 + g * 8);
            }
            bf16x8 a[4];
            #pragma unroll
            for (int mt = 0; mt < 4; ++mt) {
                int r = mt * 16 + q;
                int u = (ks * 4 + g) ^ (r & 7);
                a[mt] = *reinterpret_cast<const bf16x8*>(&sbuf[r * 128 + u * 16]);
            }
            #pragma unroll
            for (int mt = 0; mt < 4; ++mt)
                #pragma unroll
                for (int nt = 0; nt < 4; ++nt)
                    acc[mt][nt] = __builtin_amdgcn_mfma_f32_16x16x32_bf16(a[mt], b[nt], acc[mt][nt], 0, 0, 0);
        }
        __syncthreads();   // all sbuf reads for kt done
        if (kt < 3) {
            *reinterpret_cast<uint4*>(&sbuf[t * 16])         = nx0;
            *reinterpret_cast<uint4*>(&sbuf[(t + 256) * 16]) = nx1;
            __syncthreads();
        }
    }

    // ---- write f2 to f2l (swizzled, 512B rows)
    const bool evenq = (q & 1) == 0;
    #pragma unroll
    for (int nt = 0; nt < 4; ++nt) {
        int n0  = wn * 64 + nt * 16 + q;
        int n_e = n0 & ~1;
        float2 bv = *reinterpret_cast<const float2*>(b2 + n_e);
        #pragma unroll
        for (int mt = 0; mt < 4; ++mt) {
            float v[4], p[4];
            #pragma unroll
            for (int r = 0; r < 4; ++r) { v[r] = acc[mt][nt][r]; p[r] = __shfl_xor(v[r], 1, 64); }
            #pragma unroll
            for (int rr = 0; rr < 2; ++rr) {
                int r = evenq ? rr : (2 + rr);
                float lo = silu_f((evenq ? v[r] : p[r]) + bv.x);
                float hi = silu_f((evenq ? p[r] : v[r]) + bv.y);
                int m = mt * 16 + 4 * g + r;
                unsigned u = (unsigned)f2bf(lo) | ((unsigned)f2bf(hi) << 16);
                int byte = m * 512 + (((n_e >> 3) ^ (m & 7)) << 4) + ((n_e & 7) * 2);
                *reinterpret_cast<unsigned*>(f2l + byte) = u;
            }
        }
    }
    __syncthreads();

    // ---- E: Wf = f2 @ wf3 + b3, A-frags from f2l
    #pragma unroll
    for (int mt = 0; mt < 4; ++mt)
        #pragma unroll
        for (int nt = 0; nt < 4; ++nt) acc[mt][nt] = (f32x4){0.f, 0.f, 0.f, 0.f};

    #pragma unroll
    for (int kk = 0; kk < 8; ++kk) {
        bf16x8 b[4];
        #pragma unroll
        for (int nt = 0; nt < 4; ++nt) {
            int n = wn * 64 + nt * 16 + q;
            b[nt] = *reinterpret_cast<const bf16x8*>(Wt3 + (size_t)n * 256 + kk * 32 + g * 8);
        }
        bf16x8 a[4];
        #pragma unroll
        for (int mt = 0; mt < 4; ++mt) {
            int m = mt * 16 + q;
            int unit = (4 * kk + g) ^ (m & 7);
            a[mt] = *reinterpret_cast<const bf16x8*>(f2l + m * 512 + unit * 16);
        }
        #pragma unroll
        for (int mt = 0; mt < 4; ++mt)
            #pragma unroll
            for (int nt = 0; nt < 4; ++nt)
                acc[mt][nt] = __builtin_amdgcn_mfma_f32_16x16x32_bf16(a[mt], b[nt], acc[mt][nt], 0, 0, 0);
    }
    __syncthreads();   // all f2l/sbuf activity quiesced before obuf reuse

    // ---- epilogue: bias b3, bounce via sbuf (16 rows x 512B), 4 quarter-passes
    #pragma unroll
    for (int p = 0; p < 4; ++p) {
        #pragma unroll
        for (int nt = 0; nt < 4; ++nt) {
            int n0  = wn * 64 + nt * 16 + q;
            int n_e = n0 & ~1;
            float2 bv = *reinterpret_cast<const float2*>(b3 + n_e);
            float v[4], pp[4];
            #pragma unroll
            for (int r = 0; r < 4; ++r) { v[r] = acc[p][nt][r]; pp[r] = __shfl_xor(v[r], 1, 64); }
            #pragma unroll
            for (int rr = 0; rr < 2; ++rr) {
                int r = evenq ? rr : (2 + rr);
                float lo = (evenq ? v[r] : pp[r]) + bv.x;
                float hi = (evenq ? pp[r] : v[r]) + bv.y;
                int rl = 4 * g + r;   // 0..15
                unsigned u = (unsigned)f2bf(lo) | ((unsigned)f2bf(hi) << 16);
                *reinterpret_cast<unsigned*>(&sbuf[rl * 512 + n_e * 2]) = u;
            }
        }
        __syncthreads();
        {
            int rl = t >> 4, c2 = t & 15;
            int grow = m0 + p * 16 + rl;
            if (grow < M) {
                uint4 v0 = *reinterpret_cast<const uint4*>(&sbuf[rl * 512 + c2 * 32]);
                uint4 v1 = *reinterpret_cast<const uint4*>(&sbuf[rl * 512 + c2 * 32 + 16]);
                *reinterpret_cast<uint4*>(out + (size_t)grow * 256 + c2 * 16)     = v0;
                *reinterpret_cast<uint4*>(out + (size_t)grow * 256 + c2 * 16 + 8) = v1;
            }
        }
        __syncthreads();
    }
}

// ---------------------------------------------------------------------------
// F: agg per node (wave per node, contiguous Wf rows).
// ---------------------------------------------------------------------------
__global__ __launch_bounds__(256)
void agg_node_kernel(const ushort_t* __restrict__ Wf, const int* __restrict__ colp,
                     const int* __restrict__ start, const ushort_t* __restrict__ y,
                     float* __restrict__ agg, int cs, int ce, int N)
{
    int lane = threadIdx.x & 63;
    int n    = blockIdx.x * 4 + (threadIdx.x >> 6);
    if (n >= N) return;
    int s0 = start[n], s1 = start[n + 1];
    if (s1 <= cs || s0 >= ce) return;
    int lo = (s0 > cs) ? s0 : cs;
    int hi = (s1 < ce) ? s1 : ce;

    float h0 = 0.f, h1 = 0.f, h2 = 0.f, h3 = 0.f;
    for (int s = lo; s < hi; ++s) {
        uint2 wv = *reinterpret_cast<const uint2*>(Wf + (size_t)(s - cs) * 256 + lane * 4);
        int c = colp[s];
        uint2 yv = *reinterpret_cast<const uint2*>(y + (size_t)c * 256 + lane * 4);
        h0 += bf2f((ushort_t)(wv.x & 0xffff)) * bf2f((ushort_t)(yv.x & 0xffff));
        h1 += bf2f((ushort_t)(wv.x >> 16))    * bf2f((ushort_t)(yv.x >> 16));
        h2 += bf2f((ushort_t)(wv.y & 0xffff)) * bf2f((ushort_t)(yv.y & 0xffff));
        h3 += bf2f((ushort_t)(wv.y >> 16))    * bf2f((ushort_t)(yv.y >> 16));
    }

    float* row = agg + (size_t)n * 256 + lane * 4;
    if (s0 >= cs && s1 <= ce) {
        *reinterpret_cast<float4*>(row) = make_float4(h0, h1, h2, h3);
    } else {
        unsafeAtomicAdd(&row[0], h0);
        unsafeAtomicAdd(&row[1], h1);
        unsafeAtomicAdd(&row[2], h2);
        unsafeAtomicAdd(&row[3], h3);
    }
}

// ---------------------------------------------------------------------------
// Fallback (ws too small): R7 fused CSR kernel.
// ---------------------------------------------------------------------------
template<int KS, int NT, bool SILU>
__device__ __forceinline__ void mlp_stage(const unsigned char* in, unsigned char* out,
                                          const ushort_t* __restrict__ Wt,
                                          const float* __restrict__ bias,
                                          int wn, int g, int q)
{
    constexpr int K = KS * 32;
    f32x4 acc[2][NT];
    #pragma unroll
    for (int mt = 0; mt < 2; ++mt)
        #pragma unroll
        for (int nt = 0; nt < NT; ++nt) acc[mt][nt] = (f32x4){0.f, 0.f, 0.f, 0.f};

    #pragma unroll
    for (int kk = 0; kk < KS; ++kk) {
        bf16x8 b[NT];
        #pragma unroll
        for (int nt = 0; nt < NT; ++nt) {
            int n = (wn * NT + nt) * 16 + q;
            b[nt] = *reinterpret_cast<const bf16x8*>(Wt + n * K + kk * 32 + g * 8);
        }
        bf16x8 a[2];
        #pragma unroll
        for (int mt = 0; mt < 2; ++mt) {
            int m = mt * 16 + q;
            int unit = (4 * kk + g) ^ (m & 7);
            a[mt] = *reinterpret_cast<const bf16x8*>(in + m * 512 + unit * 16);
        }
        #pragma unroll
        for (int mt = 0; mt < 2; ++mt)
            #pragma unroll
            for (int nt = 0; nt < NT; ++nt)
                acc[mt][nt] = __builtin_amdgcn_mfma_f32_16x16x32_bf16(a[mt], b[nt], acc[mt][nt], 0, 0, 0);
    }

    const bool evenq = (q & 1) == 0;
    #pragma unroll
    for (int nt = 0; nt < NT; ++nt) {
        int n0  = (wn * NT + nt) * 16 + q;
        int n_e = n0 & ~1;
        float2 bv = *reinterpret_cast<const float2*>(bias + n_e);
        #pragma unroll
        for (int mt = 0; mt < 2; ++mt) {
            float v[4], p[4];
            #pragma unroll
            for (int r = 0; r < 4; ++r) { v[r] = acc[mt][nt][r]; p[r] = __shfl_xor(v[r], 1, 64); }
            #pragma unroll
            for (int rr = 0; rr < 2; ++rr) {
                int r = evenq ? rr : (2 + rr);
                float lo = (evenq ? v[r] : p[r]) + bv.x;
                float hi = (evenq ? p[r] : v[r]) + bv.y;
                if (SILU) { lo = silu_f(lo); hi = silu_f(hi); }
                int m = mt * 16 + 4 * g + r;
                unsigned u = (unsigned)f2bf(lo) | ((unsigned)f2bf(hi) << 16);
                int byte = m * 512 + (((n_e >> 3) ^ (m & 7)) << 4) + ((n_e & 7) * 2);
                *reinterpret_cast<unsigned*>(out + byte) = u;
            }
        }
    }
}

__global__ __launch_bounds__(256, 4)
void edge_csr_kernel(const float* __restrict__ distp, const int* __restrict__ colp,
                     const int* __restrict__ nodep, const int* __restrict__ start,
                     const float* __restrict__ centers, const float* __restrict__ widths,
                     const ushort_t* __restrict__ wt_rbf1, const float* __restrict__ rbf_b1,
                     const ushort_t* __restrict__ wt_comb, const float* __restrict__ b_comb,
                     const ushort_t* __restrict__ wt_f2, const float* __restrict__ filt_b2,
                     const ushort_t* __restrict__ wt_f3, const float* __restrict__ filt_b3,
                     const ushort_t* __restrict__ y, float* __restrict__ agg, int E)
{
    __shared__ __align__(16) unsigned char buf[32768];
    __shared__ int node_s[32];
    __shared__ int flag_s[32];
    unsigned char* bufA = buf;
    unsigned char* bufB = buf + 16384;

    const int t  = threadIdx.x;
    const int e0 = blockIdx.x * 32;
    const int wn   = t >> 6;
    const int lane = t & 63;
    const int g = lane >> 4, q = lane & 15;

    if (t < 32) {
        int ge = e0 + t;
        int nd = (ge < E) ? nodep[ge] : -1;
        node_s[t] = nd;
        int fl = 0;
        if (nd >= 0) {
            int lo = start[nd], hi = start[nd + 1];
            fl = (lo >= e0 && hi <= e0 + 32) ? 1 : 0;
        }
        flag_s[t] = fl;
    }

    const int e_own  = t >> 3;
    const int chunk  = t & 7;
    const int ge_own = e0 + e_own;
    const int col_own = (ge_own < E) ? colp[ge_own] : 0;
    uint4 yv[4];
    #pragma unroll
    for (int i = 0; i < 4; ++i)
        yv[i] = *reinterpret_cast<const uint4*>(y + (size_t)col_own * 256 + (i * 8 + chunk) * 8);

    {
        float d = (ge_own < E) ? distp[ge_own] : F_CUTOFF;
        float env = (d < F_CUTOFF) ? 0.5f * (__cosf(d * (F_PI / F_CUTOFF)) + 1.0f) : 0.0f;
        unsigned char* rowp = bufA + e_own * 512;
        int k0 = chunk * 8;
        #pragma unroll
        for (int i = 0; i < 4; ++i) {
            int n = k0 + 2 * i;
            float c0 = centers[n],     w0 = fabsf(widths[n]) + F_EPS_W;
            float c1 = centers[n + 1], w1 = fabsf(widths[n + 1]) + F_EPS_W;
            float z0 = (d - c0) / w0, z1 = (d - c1) / w1;
            float r0 = env * __expf(-0.5f * z0 * z0);
            float r1 = env * __expf(-0.5f * z1 * z1);
            unsigned u = (unsigned)f2bf(r0) | ((unsigned)f2bf(r1) << 16);
            int byte = (((n >> 3) ^ (e_own & 7)) << 4) + ((n & 7) * 2);
            *reinterpret_cast<unsigned*>(rowp + byte) = u;
        }
    }
    __syncthreads();

    mlp_stage<2, 1, true>(bufA, bufB, wt_rbf1, rbf_b1, wn, g, q);
    __syncthreads();
    mlp_stage<2, 4, true>(bufB, bufA, wt_comb, b_comb, wn, g, q);
    __syncthreads();
    mlp_stage<8, 4, true>(bufA, bufB, wt_f2, filt_b2, wn, g, q);
    __syncthreads();

    #pragma unroll
    for (int i = 0; i < 4; ++i)
        *reinterpret_cast<uint4*>(bufA + e_own * 512 + (i * 8 + chunk) * 16) = yv[i];
    __syncthreads();

    f32x4 acc[2][4];
    #pragma unroll
    for (int mt = 0; mt < 2; ++mt)
        #pragma unroll
        for (int nt = 0; nt < 4; ++nt) acc[mt][nt] = (f32x4){0.f, 0.f, 0.f, 0.f};

    #pragma unroll
    for (int kk = 0; kk < 8; ++kk) {
        bf16x8 b[4];
        #pragma unroll
        for (int nt = 0; nt < 4; ++nt) {
            int n = (wn * 4 + nt) * 16 + q;
            b[nt] = *reinterpret_cast<const bf16x8*>(wt_f3 + n * 256 + kk * 32 + g * 8);
        }
        bf16x8 a[2];
        #pragma unroll
        for (int mt = 0; mt < 2; ++mt) {
            int m = mt * 16 + q;
            int unit = (4 * kk + g) ^ (m & 7);
            a[mt] = *reinterpret_cast<const bf16x8*>(bufB + m * 512 + unit * 16);
        }
        #pragma unroll
        for (int mt = 0; mt < 2; ++mt)
            #pragma unroll
            for (int nt = 0; nt < 4; ++nt)
                acc[mt][nt] = __builtin_amdgcn_mfma_f32_16x16x32_bf16(a[mt], b[nt], acc[mt][nt], 0, 0, 0);
    }

    float bn[4];
    int   nn[4];
    #pragma unroll
    for (int nt = 0; nt < 4; ++nt) { nn[nt] = (wn * 4 + nt) * 16 + q; bn[nt] = filt_b3[nn[nt]]; }

    #pragma unroll
    for (int mt = 0; mt < 2; ++mt) {
        #pragma unroll
        for (int r = 0; r < 4; ++r) {
            int m = mt * 16 + 4 * g + r;
            const unsigned char* yrow = bufA + m * 512;
            #pragma unroll
            for (int nt = 0; nt < 4; ++nt) {
                float yvv = bf2f(*reinterpret_cast<const ushort_t*>(yrow + nn[nt] * 2));
                acc[mt][nt][r] = (acc[mt][nt][r] + bn[nt]) * yvv;
            }
        }
    }
    __syncthreads();

    float* msgf = reinterpret_cast<float*>(buf);
    #pragma unroll
    for (int mt = 0; mt < 2; ++mt) {
        #pragma unroll
        for (int r = 0; r < 4; ++r) {
            int m = mt * 16 + 4 * g + r;
            #pragma unroll
            for (int nt = 0; nt < 4; ++nt)
                msgf[m * 256 + nn[nt]] = acc[mt][nt][r];
        }
    }
    __syncthreads();

    {
        const int j = t;
        float accv = 0.f;
        int cur = -2, rs = 0;
        #pragma unroll 4
        for (int r = 0; r < 32; ++r) {
            int nd = node_s[r];
            if (nd != cur) {
                if (cur >= 0) {
                    if (flag_s[rs]) agg[(size_t)cur * 256 + j] = accv;
                    else            unsafeAtomicAdd(&agg[(size_t)cur * 256 + j], accv);
                }
                cur = nd; rs = r; accv = msgf[r * 256 + j];
            } else {
                accv += msgf[r * 256 + j];
            }
        }
        if (cur >= 0) {
            if (flag_s[rs]) agg[(size_t)cur * 256 + j] = accv;
            else            unsafeAtomicAdd(&agg[(size_t)cur * 256 + j], accv);
        }
    }
}

// ---------------------------------------------------------------------------
// LN in-place: d_out = LN(x + d_out) * g + b; also emits bf16 copy.
// ---------------------------------------------------------------------------
__global__ __launch_bounds__(256)
void ln_kernel(const float* __restrict__ x, const float* __restrict__ agg,
               const float* __restrict__ g, const float* __restrict__ b,
               float* __restrict__ out0, ushort_t* __restrict__ out_bf, int N)
{
    int lane = threadIdx.x & 63;
    int row  = blockIdx.x * 4 + (threadIdx.x >> 6);
    if (row >= N) return;
    float4 hx = reinterpret_cast<const float4*>(x)[row * 64 + lane];
    float4 ha = reinterpret_cast<const float4*>(agg)[row * 64 + lane];
    float4 h  = make_float4(hx.x + ha.x, hx.y + ha.y, hx.z + ha.z, hx.w + ha.w);
    float s  = h.x + h.y + h.z + h.w;
    float s2 = h.x * h.x + h.y * h.y + h.z * h.z + h.w * h.w;
    #pragma unroll
    for (int off = 32; off > 0; off >>= 1) {
        s  += __shfl_xor(s,  off, 64);
        s2 += __shfl_xor(s2, off, 64);
    }
    float mu  = s * (1.0f / 256.0f);
    float var = s2 * (1.0f / 256.0f) - mu * mu;
    float inv = rsqrtf(var + F_EPS_LN);
    float4 gv = reinterpret_cast<const float4*>(g)[lane];
    float4 bv = reinterpret_cast<const float4*>(b)[lane];
    float4 o;
    o.x = (h.x - mu) * inv * gv.x + bv.x;
    o.y = (h.y - mu) * inv * gv.y + bv.y;
    o.z = (h.z - mu) * inv * gv.z + bv.z;
    o.w = (h.w - mu) * inv * gv.w + bv.w;
    reinterpret_cast<float4*>(out0)[row * 64 + lane] = o;
    ushort_t ob[4] = {f2bf(o.x), f2bf(o.y), f2bf(o.z), f2bf(o.w)};
    *reinterpret_cast<uint2*>(out_bf + (size_t)row * 256 + lane * 4) = *reinterpret_cast<uint2*>(ob);
}

// ---------------------------------------------------------------------------
extern "C" void kernel_launch(void* const* d_in, const int* in_sizes, int n_in,
                              void* d_out, int out_size, void* d_ws, size_t ws_size,
                              hipStream_t stream)
{
    const float* x       = (const float*)d_in[0];
    const int*   eidx    = (const int*)  d_in[1];
    const float* dist    = (const float*)d_in[2];
    const float* centers = (const float*)d_in[3];
    const float* widths  = (const float*)d_in[4];
    const float* rbf_w1  = (const float*)d_in[5];
    const float* rbf_b1  = (const float*)d_in[6];
    const float* rbf_w2  = (const float*)d_in[7];
    const float* rbf_b2  = (const float*)d_in[8];
    const float* filt_w1 = (const float*)d_in[9];
    const float* filt_b1 = (const float*)d_in[10];
    const float* filt_w2 = (const float*)d_in[11];
    const float* filt_b2 = (const float*)d_in[12];
    const float* filt_w3 = (const float*)d_in[13];
    const float* filt_b3 = (const float*)d_in[14];
    const float* node_w  = (const float*)d_in[15];
    const float* node_b  = (const float*)d_in[16];
    const float* ln_g    = (const float*)d_in[17];
    const float* ln_b    = (const float*)d_in[18];
    const float* gate_w  = (const float*)d_in[19];
    const float* gate_b  = (const float*)d_in[20];

    const int N = in_sizes[0] / 256;
    const int E = in_sizes[2];

    char* wsb = (char*)d_ws;
    size_t off = 0;
    auto alloc = [&](size_t bytes, size_t align) -> char* {
        off = (off + align - 1) & ~(align - 1);
        char* p = wsb + off;
        off += bytes;
        return p;
    };
    ushort_t* y_bf   = (ushort_t*)alloc((size_t)N * 256 * 2, 16);
    ushort_t* wt1    = (ushort_t*)alloc(64 * 64 * 2, 16);
    ushort_t* wcomb  = (ushort_t*)alloc(256 * 64 * 2, 16);
    ushort_t* wf2t   = (ushort_t*)alloc(256 * 256 * 2, 16);
    ushort_t* wf3t   = (ushort_t*)alloc(256 * 256 * 2, 16);
    ushort_t* wnodet = (ushort_t*)alloc(256 * 256 * 2, 16);
    ushort_t* wgatet = (ushort_t*)alloc(256 * 256 * 2, 16);
    float*    bcomb  = (float*)   alloc(256 * 4, 16);
    int*      part   = (int*)     alloc(256 * 4, 16);
    int*      cnt    = (int*)     alloc((size_t)N * 4, 16);
    int*      start  = (int*)     alloc(((size_t)N + 1) * 4, 16);
    int*      colp   = (int*)     alloc((size_t)E * 4, 16);
    int*      nodep  = (int*)     alloc((size_t)E * 4, 16);
    float*    distp  = (float*)   alloc((size_t)E * 4, 256);

    size_t fixed_off = (off + 1023) & ~(size_t)1023;
    size_t avail = (ws_size > fixed_off) ? (ws_size - fixed_off) : 0;
    // per-row: rt (t1) 128B + fw (f1->Wf, in-place) 512B
    long Rl = (long)(avail / 640);
    int R = (int)(Rl & ~127L);
    int Eround = (E + 127) & ~127;
    if (R > Eround) R = Eround;
    const bool dense = (R >= 128) && ((E + R - 1) / R <= 8)
                       && ((size_t)R * 640 >= (size_t)N * 512 + 1024);
    ushort_t* rt_buf = (ushort_t*)(wsb + fixed_off);
    ushort_t* fw_buf = rt_buf + (size_t)R * 64;
    ushort_t* x_bf   = rt_buf;   // alias: used only before chunk loop
    ushort_t* a_bf   = rt_buf;   // alias: used only after chunk loop

    dim3 b256(256);
    const int range = (N + 255) / 256;

    // weight prep
    cvt_transpose_kernel<<<dim3((64 * 64 + 255) / 256),   b256, 0, stream>>>(rbf_w1,  wt1, 64, 64, 6);
    combine_w_kernel<<<dim3(64), b256, 0, stream>>>(rbf_w2, filt_w1, wcomb);
    combine_b_kernel<<<dim3(1), b256, 0, stream>>>(rbf_b2, filt_w1, filt_b1, bcomb);
    cvt_transpose_kernel<<<dim3((256 * 256 + 255) / 256), b256, 0, stream>>>(filt_w2, wf2t, 256, 256, 8);
    cvt_transpose_kernel<<<dim3((256 * 256 + 255) / 256), b256, 0, stream>>>(filt_w3, wf3t, 256, 256, 8);
    cvt_transpose_kernel<<<dim3((256 * 256 + 255) / 256), b256, 0, stream>>>(node_w,  wnodet, 256, 256, 8);
    cvt_transpose_kernel<<<dim3((256 * 256 + 255) / 256), b256, 0, stream>>>(gate_w,  wgatet, 256, 256, 8);

    hipMemsetAsync(d_out, 0, (size_t)out_size * sizeof(float), stream);
    hipMemsetAsync(cnt, 0, (size_t)N * 4, stream);

    if (dense) {
        cast_bf16_kernel<<<dim3((N * 64 + 255) / 256), b256, 0, stream>>>(x, x_bf, (long)N * 64);
        gemm_k256_kernel<false><<<dim3((N + 63) / 64), b256, 0, stream>>>(
            x_bf, wnodet, node_b, y_bf, N);
    } else {
        gemm256_bf16_kernel<<<dim3((N + 63) / 64), b256, 0, stream>>>(x, node_w, node_b, y_bf, N);
    }

    // CSR build
    count_kernel<<<dim3((E + 255) / 256), b256, 0, stream>>>(eidx, cnt, E);
    scan_sum_kernel<<<dim3(256), b256, 0, stream>>>(cnt, part, N, range);
    scan_write_kernel<<<dim3(1), b256, 0, stream>>>(part, cnt, start, N, range, E);
    scatter_kernel<<<dim3((E + 255) / 256), b256, 0, stream>>>(eidx, dist, cnt, colp, nodep, distp, E);

    if (dense) {
        for (int cs = 0; cs < E; cs += R) {
            int Mc = (E - cs < R) ? (E - cs) : R;
            rbf_t1_kernel<<<dim3((Mc + 127) / 128), b256, 0, stream>>>(
                distp + cs, centers, widths, wt1, rbf_b1, rt_buf, Mc);   // dist -> t1 (RBF fused)
            gemm_k64n256_kernel<<<dim3((Mc + 63) / 64), b256, 0, stream>>>(
                rt_buf, wcomb, bcomb, fw_buf, Mc);                       // t1 -> f1
            fused_de_kernel<<<dim3((Mc + 63) / 64), b256, 0, stream>>>(
                fw_buf, wf2t, filt_b2, wf3t, filt_b3, fw_buf, Mc);       // f1 -> Wf in-place
            agg_node_kernel<<<dim3((N + 3) / 4), b256, 0, stream>>>(
                fw_buf, colp, start, y_bf, (float*)d_out, cs, cs + Mc, N);
        }
        ln_kernel<<<dim3((N + 3) / 4), b256, 0, stream>>>(
            x, (float*)d_out, ln_g, ln_b, (float*)d_out, a_bf, N);
        gate_mfma_kernel<<<dim3((N + 63) / 64), b256, 0, stream>>>(
            a_bf, wgatet, gate_b, (float*)d_out, N);
    } else {
        edge_csr_kernel<<<dim3((E + 31) / 32), b256, 0, stream>>>(
            distp, colp, nodep, start, centers, widths,
            wt1, rbf_b1, wcomb, bcomb,
            wf2t, filt_b2, wf3t, filt_b3,
            y_bf, (float*)d_out, E);
        ln_kernel<<<dim3((N + 3) / 4), b256, 0, stream>>>(
            x, (float*)d_out, ln_g, ln_b, (float*)d_out, y_bf, N);
        gate_gemm_kernel<<<dim3((N + 63) / 64), b256, 0, stream>>>(
            (float*)d_out, gate_w, gate_b, (float*)d_out, N);
    }
}

// Round 13
// 853.258 us; speedup vs baseline: 1.0545x; 1.0545x over previous
//
#include <hip/hip_runtime.h>
#include <hip/hip_bf16.h>
#include <math.h>

typedef __attribute__((ext_vector_type(8))) short bf16x8;
typedef __attribute__((ext_vector_type(4))) float f32x4;
typedef unsigned short ushort_t;

constexpr float F_CUTOFF = 10.0f;
constexpr float F_EPS_W  = 1e-5f;
constexpr float F_EPS_LN = 1e-5f;
constexpr float F_PI     = 3.14159265358979323846f;

__device__ __forceinline__ float silu_f(float v)   { return v / (1.0f + __expf(-v)); }
__device__ __forceinline__ float sigmoid_f(float v){ return 1.0f / (1.0f + __expf(-v)); }

__device__ __forceinline__ ushort_t f2bf(float f) {
    union { __hip_bfloat16 h; ushort_t u; } v; v.h = __float2bfloat16(f); return v.u;
}
__device__ __forceinline__ float bf2f(ushort_t u) {
    union { unsigned u; float f; } v; v.u = ((unsigned)u) << 16; return v.f;
}

// ---------------------------------------------------------------------------
// CSR build (parallel scan) — proven R8
// ---------------------------------------------------------------------------
__global__ void count_kernel(const int* __restrict__ eidx, int* __restrict__ cnt, int E)
{
    int e = blockIdx.x * 256 + threadIdx.x;
    if (e < E) atomicAdd(&cnt[eidx[e]], 1);
}

__global__ __launch_bounds__(256)
void scan_sum_kernel(const int* __restrict__ cnt, int* __restrict__ part, int N, int range)
{
    __shared__ int red[256];
    int base = blockIdx.x * range;
    int s = 0;
    for (int i = threadIdx.x; i < range; i += 256) {
        int idx = base + i;
        if (idx < N) s += cnt[idx];
    }
    red[threadIdx.x] = s;
    __syncthreads();
    #pragma unroll
    for (int o = 128; o > 0; o >>= 1) {
        if (threadIdx.x < o) red[threadIdx.x] += red[threadIdx.x + o];
        __syncthreads();
    }
    if (threadIdx.x == 0) part[blockIdx.x] = red[0];
}

__global__ __launch_bounds__(256)
void scan_write_kernel(const int* __restrict__ part, int* __restrict__ cnt /*->cursor*/,
                       int* __restrict__ start, int N, int range, int E)
{
    __shared__ int ex[256];
    int tid = threadIdx.x;
    int v = part[tid];
    ex[tid] = v;
    __syncthreads();
    for (int o = 1; o < 256; o <<= 1) {
        int add = (tid >= o) ? ex[tid - o] : 0;
        __syncthreads();
        ex[tid] += add;
        __syncthreads();
    }
    int run = ex[tid] - v;
    int base = tid * range;
    for (int i = 0; i < range; ++i) {
        int idx = base + i;
        if (idx < N) {
            int c = cnt[idx];
            start[idx] = run;
            cnt[idx] = run;
            run += c;
        }
    }
    if (tid == 0) start[N] = E;
}

__global__ void scatter_kernel(const int* __restrict__ eidx, const float* __restrict__ dist,
                               int* __restrict__ cursor,
                               int* __restrict__ colp, int* __restrict__ nodep,
                               float* __restrict__ distp, int E)
{
    int e = blockIdx.x * 256 + threadIdx.x;
    if (e < E) {
        int row = eidx[e];
        int s = atomicAdd(&cursor[row], 1);
        colp[s]  = eidx[E + e];
        nodep[s] = row;
        distp[s] = dist[e];
    }
}

// ---------------------------------------------------------------------------
// Weight prep / casts
// ---------------------------------------------------------------------------
__global__ void cvt_transpose_kernel(const float* __restrict__ in, ushort_t* __restrict__ out,
                                     int K, int N, int logK)
{
    int idx = blockIdx.x * 256 + threadIdx.x;
    if (idx >= K * N) return;
    int n = idx >> logK;
    int k = idx & (K - 1);
    out[idx] = f2bf(in[k * N + n]);
}

__global__ void combine_w_kernel(const float* __restrict__ w2, const float* __restrict__ fw1,
                                 ushort_t* __restrict__ out)
{
    int idx = blockIdx.x * 256 + threadIdx.x;
    int c = idx >> 6, j = idx & 63;
    float s = 0.f;
    #pragma unroll 8
    for (int n = 0; n < 64; ++n) s += w2[j * 64 + n] * fw1[n * 256 + c];
    out[idx] = f2bf(s);
}

__global__ void combine_b_kernel(const float* __restrict__ b2, const float* __restrict__ fw1,
                                 const float* __restrict__ fb1, float* __restrict__ out)
{
    int c = threadIdx.x;
    float s = fb1[c];
    #pragma unroll 8
    for (int n = 0; n < 64; ++n) s += b2[n] * fw1[n * 256 + c];
    out[c] = s;
}

__global__ __launch_bounds__(256)
void cast_bf16_kernel(const float* __restrict__ in, ushort_t* __restrict__ out, long n4)
{
    long i = (long)blockIdx.x * 256 + threadIdx.x;
    if (i >= n4) return;
    float4 v = reinterpret_cast<const float4*>(in)[i];
    ushort_t o[4] = {f2bf(v.x), f2bf(v.y), f2bf(v.z), f2bf(v.w)};
    *reinterpret_cast<uint2*>(out + i * 4) = *reinterpret_cast<uint2*>(o);
}

// ---------------------------------------------------------------------------
// Fallback y-GEMM (fp32 VALU): y = x @ node_w + node_b (bf16 out)
// ---------------------------------------------------------------------------
__global__ __launch_bounds__(256)
void gemm256_bf16_kernel(const float* __restrict__ A, const float* __restrict__ Wm,
                         const float* __restrict__ bias, ushort_t* __restrict__ out, int M)
{
    __shared__ float4 As4[64][64];
    const int t = threadIdx.x;
    const int row0 = blockIdx.x * 64;

    #pragma unroll
    for (int i = 0; i < 16; ++i) {
        int flat = t + i * 256;
        int r = flat >> 6, k4 = flat & 63;
        int row = row0 + r;
        float4 v = make_float4(0.f, 0.f, 0.f, 0.f);
        if (row < M) v = reinterpret_cast<const float4*>(A)[row * 64 + k4];
        As4[r][k4] = v;
    }
    __syncthreads();

    const int jt  = t & 31;
    const int et  = t >> 5;
    const int j04 = jt * 2;
    const int r0  = et * 8;

    float acc[8][8];
    #pragma unroll
    for (int r = 0; r < 8; ++r)
        #pragma unroll
        for (int c = 0; c < 8; ++c) acc[r][c] = 0.f;

    for (int k4 = 0; k4 < 64; ++k4) {
        float4 a4[8];
        #pragma unroll
        for (int r = 0; r < 8; ++r) a4[r] = As4[r0 + r][k4];
        #pragma unroll
        for (int q = 0; q < 4; ++q) {
            const int k = k4 * 4 + q;
            float4 b0 = reinterpret_cast<const float4*>(Wm)[k * 64 + j04];
            float4 b1 = reinterpret_cast<const float4*>(Wm)[k * 64 + j04 + 1];
            float bb[8] = {b0.x, b0.y, b0.z, b0.w, b1.x, b1.y, b1.z, b1.w};
            float av;
            #pragma unroll
            for (int r = 0; r < 8; ++r) {
                av = (q == 0) ? a4[r].x : (q == 1) ? a4[r].y : (q == 2) ? a4[r].z : a4[r].w;
                #pragma unroll
                for (int c = 0; c < 8; ++c) acc[r][c] = fmaf(av, bb[c], acc[r][c]);
            }
        }
    }

    float4 bv0 = reinterpret_cast<const float4*>(bias)[j04];
    float4 bv1 = reinterpret_cast<const float4*>(bias)[j04 + 1];
    float bb[8] = {bv0.x, bv0.y, bv0.z, bv0.w, bv1.x, bv1.y, bv1.z, bv1.w};

    #pragma unroll
    for (int r = 0; r < 8; ++r) {
        int row = row0 + r0 + r;
        if (row >= M) continue;
        ushort_t o8[8];
        #pragma unroll
        for (int c = 0; c < 8; ++c) o8[c] = f2bf(acc[r][c] + bb[c]);
        *reinterpret_cast<uint4*>(out + (size_t)row * 256 + jt * 8) = *reinterpret_cast<uint4*>(o8);
    }
}

// ---------------------------------------------------------------------------
// Fallback gate GEMM (fp32 VALU)
// ---------------------------------------------------------------------------
__global__ __launch_bounds__(256)
void gate_gemm_kernel(const float* __restrict__ A, const float* __restrict__ Wm,
                      const float* __restrict__ bias, float* __restrict__ out, int M)
{
    __shared__ float4 As4[64][64];
    const int t = threadIdx.x;
    const int row0 = blockIdx.x * 64;

    #pragma unroll
    for (int i = 0; i < 16; ++i) {
        int flat = t + i * 256;
        int r = flat >> 6, k4 = flat & 63;
        int row = row0 + r;
        float4 v = make_float4(0.f, 0.f, 0.f, 0.f);
        if (row < M) v = reinterpret_cast<const float4*>(A)[row * 64 + k4];
        As4[r][k4] = v;
    }
    __syncthreads();

    const int jt  = t & 31;
    const int et  = t >> 5;
    const int j04 = jt * 2;
    const int r0  = et * 8;

    float acc[8][8];
    #pragma unroll
    for (int r = 0; r < 8; ++r)
        #pragma unroll
        for (int c = 0; c < 8; ++c) acc[r][c] = 0.f;

    for (int k4 = 0; k4 < 64; ++k4) {
        float4 a4[8];
        #pragma unroll
        for (int r = 0; r < 8; ++r) a4[r] = As4[r0 + r][k4];
        #pragma unroll
        for (int q = 0; q < 4; ++q) {
            const int k = k4 * 4 + q;
            float4 b0 = reinterpret_cast<const float4*>(Wm)[k * 64 + j04];
            float4 b1 = reinterpret_cast<const float4*>(Wm)[k * 64 + j04 + 1];
            float bb[8] = {b0.x, b0.y, b0.z, b0.w, b1.x, b1.y, b1.z, b1.w};
            float av;
            #pragma unroll
            for (int r = 0; r < 8; ++r) {
                av = (q == 0) ? a4[r].x : (q == 1) ? a4[r].y : (q == 2) ? a4[r].z : a4[r].w;
                #pragma unroll
                for (int c = 0; c < 8; ++c) acc[r][c] = fmaf(av, bb[c], acc[r][c]);
            }
        }
    }

    float4 bv0 = reinterpret_cast<const float4*>(bias)[j04];
    float4 bv1 = reinterpret_cast<const float4*>(bias)[j04 + 1];
    float bb[8] = {bv0.x, bv0.y, bv0.z, bv0.w, bv1.x, bv1.y, bv1.z, bv1.w};

    #pragma unroll
    for (int r = 0; r < 8; ++r) {
        int row = row0 + r0 + r;
        if (row >= M) continue;
        float4 a0 = As4[r0 + r][j04];
        float4 a1 = As4[r0 + r][j04 + 1];
        float aa[8] = {a0.x, a0.y, a0.z, a0.w, a1.x, a1.y, a1.z, a1.w};
        float o[8];
        #pragma unroll
        for (int c = 0; c < 8; ++c) o[c] = aa[c] * sigmoid_f(acc[r][c] + bb[c]);
        reinterpret_cast<float4*>(out)[row * 64 + j04]     = make_float4(o[0], o[1], o[2], o[3]);
        reinterpret_cast<float4*>(out)[row * 64 + j04 + 1] = make_float4(o[4], o[5], o[6], o[7]);
    }
}

// ---------------------------------------------------------------------------
// A+B fused: t1[Mc,64] = silu(rbf(dist) @ wt1 + b1).  (R12 proven)
// ---------------------------------------------------------------------------
__global__ __launch_bounds__(256, 4)
void rbf_t1_kernel(const float* __restrict__ distp,
                   const float* __restrict__ centers, const float* __restrict__ widths,
                   const ushort_t* __restrict__ Wt, const float* __restrict__ bias,
                   ushort_t* __restrict__ out, int M)
{
    __shared__ __align__(16) unsigned char sA[128 * 128];
    const int t = threadIdx.x;
    const int m0 = blockIdx.x * 128;
    const int w = t >> 6, lane = t & 63;
    const int g = lane >> 4, q = lane & 15;

    #pragma unroll
    for (int i = 0; i < 4; ++i) {
        int s = t + i * 256;
        int r = s >> 3, u = s & 7;
        int row = m0 + r;
        float d = (row < M) ? distp[row] : F_CUTOFF;
        float env = (d < F_CUTOFF) ? 0.5f * (__cosf(d * (F_PI / F_CUTOFF)) + 1.0f) : 0.0f;
        int c0 = (u ^ (r & 7)) * 8;
        ushort_t o[8];
        #pragma unroll
        for (int j = 0; j < 8; ++j) {
            int n = c0 + j;
            float wd = fabsf(widths[n]) + F_EPS_W;
            float z = (d - centers[n]) / wd;
            o[j] = f2bf(env * __expf(-0.5f * z * z));
        }
        *reinterpret_cast<uint4*>(sA + s * 16) = *reinterpret_cast<uint4*>(o);
    }
    __syncthreads();

    f32x4 acc[2][4];
    #pragma unroll
    for (int mt = 0; mt < 2; ++mt)
        #pragma unroll
        for (int nt = 0; nt < 4; ++nt) acc[mt][nt] = (f32x4){0.f, 0.f, 0.f, 0.f};

    #pragma unroll
    for (int kk = 0; kk < 2; ++kk) {
        bf16x8 b[4];
        #pragma unroll
        for (int nt = 0; nt < 4; ++nt) {
            int n = nt * 16 + q;
            b[nt] = *reinterpret_cast<const bf16x8*>(Wt + n * 64 + kk * 32 + g * 8);
        }
        bf16x8 a[2];
        #pragma unroll
        for (int mt = 0; mt < 2; ++mt) {
            int m = w * 32 + mt * 16 + q;
            int unit = (4 * kk + g) ^ (m & 7);
            a[mt] = *reinterpret_cast<const bf16x8*>(sA + m * 128 + unit * 16);
        }
        #pragma unroll
        for (int mt = 0; mt < 2; ++mt)
            #pragma unroll
            for (int nt = 0; nt < 4; ++nt)
                acc[mt][nt] = __builtin_amdgcn_mfma_f32_16x16x32_bf16(a[mt], b[nt], acc[mt][nt], 0, 0, 0);
    }
    __syncthreads();

    const bool evenq = (q & 1) == 0;
    #pragma unroll
    for (int nt = 0; nt < 4; ++nt) {
        int n0  = nt * 16 + q;
        int n_e = n0 & ~1;
        float2 bv = *reinterpret_cast<const float2*>(bias + n_e);
        #pragma unroll
        for (int mt = 0; mt < 2; ++mt) {
            float v[4], p[4];
            #pragma unroll
            for (int r = 0; r < 4; ++r) { v[r] = acc[mt][nt][r]; p[r] = __shfl_xor(v[r], 1, 64); }
            #pragma unroll
            for (int rr = 0; rr < 2; ++rr) {
                int r = evenq ? rr : (2 + rr);
                float lo = silu_f((evenq ? v[r] : p[r]) + bv.x);
                float hi = silu_f((evenq ? p[r] : v[r]) + bv.y);
                int m = w * 32 + mt * 16 + 4 * g + r;
                unsigned u = (unsigned)f2bf(lo) | ((unsigned)f2bf(hi) << 16);
                *reinterpret_cast<unsigned*>(sA + m * 128 + n_e * 2) = u;
            }
        }
    }
    __syncthreads();

    {
        int row = t >> 1, j = t & 1;
        if (m0 + row < M) {
            #pragma unroll
            for (int i = 0; i < 4; ++i) {
                uint4 v = *reinterpret_cast<const uint4*>(sA + row * 128 + (j * 4 + i) * 16);
                *reinterpret_cast<uint4*>(out + (size_t)(m0 + row) * 64 + (j * 4 + i) * 8) = v;
            }
        }
    }
}

// ---------------------------------------------------------------------------
// C: f1[Mc,256] = silu(t1 @ wcomb + bcomb).  K=64, N=256, BM=64.
// ---------------------------------------------------------------------------
__global__ __launch_bounds__(256, 4)
void gemm_k64n256_kernel(const ushort_t* __restrict__ A, const ushort_t* __restrict__ Wt,
                         const float* __restrict__ bias, ushort_t* __restrict__ out, int M)
{
    __shared__ __align__(16) unsigned char sA[64 * 128];
    __shared__ __align__(16) unsigned char obuf[32 * 512];
    const int t = threadIdx.x;
    const int m0 = blockIdx.x * 64;
    const int wn = t >> 6, lane = t & 63;
    const int g = lane >> 4, q = lane & 15;

    #pragma unroll
    for (int i = 0; i < 2; ++i) {
        int s = t + i * 256;
        int r = s >> 3, u = s & 7;
        int row = m0 + r; row = (row < M) ? row : (M - 1);
        uint4 v = *reinterpret_cast<const uint4*>(A + (size_t)row * 64 + ((u ^ (r & 7)) * 8));
        *reinterpret_cast<uint4*>(sA + s * 16) = v;
    }
    __syncthreads();

    f32x4 acc[4][4];
    #pragma unroll
    for (int mt = 0; mt < 4; ++mt)
        #pragma unroll
        for (int nt = 0; nt < 4; ++nt) acc[mt][nt] = (f32x4){0.f, 0.f, 0.f, 0.f};

    #pragma unroll
    for (int kk = 0; kk < 2; ++kk) {
        bf16x8 b[4];
        #pragma unroll
        for (int nt = 0; nt < 4; ++nt) {
            int n = wn * 64 + nt * 16 + q;
            b[nt] = *reinterpret_cast<const bf16x8*>(Wt + n * 64 + kk * 32 + g * 8);
        }
        bf16x8 a[4];
        #pragma unroll
        for (int mt = 0; mt < 4; ++mt) {
            int m = mt * 16 + q;
            int unit = (4 * kk + g) ^ (m & 7);
            a[mt] = *reinterpret_cast<const bf16x8*>(sA + m * 128 + unit * 16);
        }
        #pragma unroll
        for (int mt = 0; mt < 4; ++mt)
            #pragma unroll
            for (int nt = 0; nt < 4; ++nt)
                acc[mt][nt] = __builtin_amdgcn_mfma_f32_16x16x32_bf16(a[mt], b[nt], acc[mt][nt], 0, 0, 0);
    }

    const bool evenq = (q & 1) == 0;
    #pragma unroll
    for (int half = 0; half < 2; ++half) {
        #pragma unroll
        for (int mtl = 0; mtl < 2; ++mtl) {
            int mt = half * 2 + mtl;
            #pragma unroll
            for (int nt = 0; nt < 4; ++nt) {
                int n0  = wn * 64 + nt * 16 + q;
                int n_e = n0 & ~1;
                float2 bv = *reinterpret_cast<const float2*>(bias + n_e);
                float v[4], p[4];
                #pragma unroll
                for (int r = 0; r < 4; ++r) { v[r] = acc[mt][nt][r]; p[r] = __shfl_xor(v[r], 1, 64); }
                #pragma unroll
                for (int rr = 0; rr < 2; ++rr) {
                    int r = evenq ? rr : (2 + rr);
                    float lo = silu_f((evenq ? v[r] : p[r]) + bv.x);
                    float hi = silu_f((evenq ? p[r] : v[r]) + bv.y);
                    int ml = mtl * 16 + 4 * g + r;
                    unsigned u = (unsigned)f2bf(lo) | ((unsigned)f2bf(hi) << 16);
                    *reinterpret_cast<unsigned*>(obuf + ml * 512 + n_e * 2) = u;
                }
            }
        }
        __syncthreads();
        {
            int row = t >> 3, c = t & 7;
            int grow = m0 + half * 32 + row;
            if (grow < M) {
                #pragma unroll
                for (int i = 0; i < 4; ++i) {
                    uint4 v = *reinterpret_cast<const uint4*>(obuf + row * 512 + (c + 8 * i) * 16);
                    *reinterpret_cast<uint4*>(out + (size_t)grow * 256 + (c + 8 * i) * 8) = v;
                }
            }
        }
        __syncthreads();
    }
}

// ---------------------------------------------------------------------------
// gemm_k256<SILU>: out[M,256] = act(A[M,256] @ W + bias), bf16 in/out.
// ---------------------------------------------------------------------------
template<bool SILU>
__global__ __launch_bounds__(256, 4)
void gemm_k256_kernel(const ushort_t* __restrict__ A, const ushort_t* __restrict__ Wt,
                      const float* __restrict__ bias, ushort_t* __restrict__ out, int M)
{
    __shared__ __align__(16) unsigned char sbuf[2][8192];

    const int t  = threadIdx.x;
    const int m0 = blockIdx.x * 64;
    const int wn   = t >> 6;
    const int lane = t & 63;
    const int g = lane >> 4, q = lane & 15;

    const int s0r = t >> 3,         s0u = t & 7;
    const int s1r = (t + 256) >> 3, s1u = t & 7;
    const ushort_t* src0base = A + (size_t)((m0 + s0r < M) ? (m0 + s0r) : (M - 1)) * 256 + ((s0u ^ (s0r & 7)) * 8);
    const ushort_t* src1base = A + (size_t)((m0 + s1r < M) ? (m0 + s1r) : (M - 1)) * 256 + ((s1u ^ (s1r & 7)) * 8);

    uint4 p0 = *reinterpret_cast<const uint4*>(src0base);
    uint4 p1 = *reinterpret_cast<const uint4*>(src1base);
    *reinterpret_cast<uint4*>(&sbuf[0][t * 16])         = p0;
    *reinterpret_cast<uint4*>(&sbuf[0][(t + 256) * 16]) = p1;
    __syncthreads();

    f32x4 acc[4][4];
    #pragma unroll
    for (int mt = 0; mt < 4; ++mt)
        #pragma unroll
        for (int nt = 0; nt < 4; ++nt) acc[mt][nt] = (f32x4){0.f, 0.f, 0.f, 0.f};

    for (int kt = 0; kt < 4; ++kt) {
        const int cur = kt & 1;
        uint4 nx0, nx1;
        if (kt < 3) {
            nx0 = *reinterpret_cast<const uint4*>(src0base + (kt + 1) * 64);
            nx1 = *reinterpret_cast<const uint4*>(src1base + (kt + 1) * 64);
        }
        #pragma unroll
        for (int ks = 0; ks < 2; ++ks) {
            bf16x8 b[4];
            #pragma unroll
            for (int nt = 0; nt < 4; ++nt) {
                int n = wn * 64 + nt * 16 + q;
                b[nt] = *reinterpret_cast<const bf16x8*>(Wt + (size_t)n * 256 + kt * 64 + ks * 32 + g * 8);
            }
            bf16x8 a[4];
            #pragma unroll
            for (int mt = 0; mt < 4; ++mt) {
                int r = mt * 16 + q;
                int u = (ks * 4 + g) ^ (r & 7);
                a[mt] = *reinterpret_cast<const bf16x8*>(&sbuf[cur][r * 128 + u * 16]);
            }
            #pragma unroll
            for (int mt = 0; mt < 4; ++mt)
                #pragma unroll
                for (int nt = 0; nt < 4; ++nt)
                    acc[mt][nt] = __builtin_amdgcn_mfma_f32_16x16x32_bf16(a[mt], b[nt], acc[mt][nt], 0, 0, 0);
        }
        __syncthreads();
        if (kt < 3) {
            *reinterpret_cast<uint4*>(&sbuf[cur ^ 1][t * 16])         = nx0;
            *reinterpret_cast<uint4*>(&sbuf[cur ^ 1][(t + 256) * 16]) = nx1;
            __syncthreads();
        }
    }

    unsigned char* obuf = &sbuf[0][0];
    const bool evenq = (q & 1) == 0;
    #pragma unroll
    for (int half = 0; half < 2; ++half) {
        __syncthreads();
        #pragma unroll
        for (int mtl = 0; mtl < 2; ++mtl) {
            int mt = half * 2 + mtl;
            #pragma unroll
            for (int nt = 0; nt < 4; ++nt) {
                int n0  = wn * 64 + nt * 16 + q;
                int n_e = n0 & ~1;
                float2 bv = *reinterpret_cast<const float2*>(bias + n_e);
                float v[4], p[4];
                #pragma unroll
                for (int r = 0; r < 4; ++r) { v[r] = acc[mt][nt][r]; p[r] = __shfl_xor(v[r], 1, 64); }
                #pragma unroll
                for (int rr = 0; rr < 2; ++rr) {
                    int r = evenq ? rr : (2 + rr);
                    float lo = (evenq ? v[r] : p[r]) + bv.x;
                    float hi = (evenq ? p[r] : v[r]) + bv.y;
                    if (SILU) { lo = silu_f(lo); hi = silu_f(hi); }
                    int ml = mtl * 16 + 4 * g + r;
                    unsigned u = (unsigned)f2bf(lo) | ((unsigned)f2bf(hi) << 16);
                    *reinterpret_cast<unsigned*>(obuf + ml * 512 + n_e * 2) = u;
                }
            }
        }
        __syncthreads();
        {
            int row = t >> 3, c = t & 7;
            int grow = m0 + half * 32 + row;
            if (grow < M) {
                #pragma unroll
                for (int i = 0; i < 4; ++i) {
                    uint4 v = *reinterpret_cast<const uint4*>(obuf + row * 512 + (c + 8 * i) * 16);
                    *reinterpret_cast<uint4*>(out + (size_t)grow * 256 + (c + 8 * i) * 8) = v;
                }
            }
        }
    }
}

// ---------------------------------------------------------------------------
// Gate MFMA: d_out = d_out * sigmoid(a_bf @ gate_w + gb).  (R11 proven)
// ---------------------------------------------------------------------------
__global__ __launch_bounds__(256, 4)
void gate_mfma_kernel(const ushort_t* __restrict__ A, const ushort_t* __restrict__ Wt,
                      const float* __restrict__ bias, float* __restrict__ out, int M)
{
    __shared__ __align__(16) unsigned char sbuf[2][8192];
    __shared__ float obuf[16][260];

    const int t  = threadIdx.x;
    const int m0 = blockIdx.x * 64;
    const int wn   = t >> 6;
    const int lane = t & 63;
    const int g = lane >> 4, q = lane & 15;

    const int s0r = t >> 3,         s0u = t & 7;
    const int s1r = (t + 256) >> 3, s1u = t & 7;
    const ushort_t* src0base = A + (size_t)((m0 + s0r < M) ? (m0 + s0r) : (M - 1)) * 256 + ((s0u ^ (s0r & 7)) * 8);
    const ushort_t* src1base = A + (size_t)((m0 + s1r < M) ? (m0 + s1r) : (M - 1)) * 256 + ((s1u ^ (s1r & 7)) * 8);

    uint4 p0 = *reinterpret_cast<const uint4*>(src0base);
    uint4 p1 = *reinterpret_cast<const uint4*>(src1base);
    *reinterpret_cast<uint4*>(&sbuf[0][t * 16])         = p0;
    *reinterpret_cast<uint4*>(&sbuf[0][(t + 256) * 16]) = p1;
    __syncthreads();

    f32x4 acc[4][4];
    #pragma unroll
    for (int mt = 0; mt < 4; ++mt)
        #pragma unroll
        for (int nt = 0; nt < 4; ++nt) acc[mt][nt] = (f32x4){0.f, 0.f, 0.f, 0.f};

    for (int kt = 0; kt < 4; ++kt) {
        const int cur = kt & 1;
        uint4 nx0, nx1;
        if (kt < 3) {
            nx0 = *reinterpret_cast<const uint4*>(src0base + (kt + 1) * 64);
            nx1 = *reinterpret_cast<const uint4*>(src1base + (kt + 1) * 64);
        }
        #pragma unroll
        for (int ks = 0; ks < 2; ++ks) {
            bf16x8 b[4];
            #pragma unroll
            for (int nt = 0; nt < 4; ++nt) {
                int n = wn * 64 + nt * 16 + q;
                b[nt] = *reinterpret_cast<const bf16x8*>(Wt + (size_t)n * 256 + kt * 64 + ks * 32 + g * 8);
            }
            bf16x8 a[4];
            #pragma unroll
            for (int mt = 0; mt < 4; ++mt) {
                int r = mt * 16 + q;
                int u = (ks * 4 + g) ^ (r & 7);
                a[mt] = *reinterpret_cast<const bf16x8*>(&sbuf[cur][r * 128 + u * 16]);
            }
            #pragma unroll
            for (int mt = 0; mt < 4; ++mt)
                #pragma unroll
                for (int nt = 0; nt < 4; ++nt)
                    acc[mt][nt] = __builtin_amdgcn_mfma_f32_16x16x32_bf16(a[mt], b[nt], acc[mt][nt], 0, 0, 0);
        }
        __syncthreads();
        if (kt < 3) {
            *reinterpret_cast<uint4*>(&sbuf[cur ^ 1][t * 16])         = nx0;
            *reinterpret_cast<uint4*>(&sbuf[cur ^ 1][(t + 256) * 16]) = nx1;
            __syncthreads();
        }
    }

    float bn[4];
    #pragma unroll
    for (int nt = 0; nt < 4; ++nt) bn[nt] = bias[wn * 64 + nt * 16 + q];

    #pragma unroll
    for (int p = 0; p < 4; ++p) {
        #pragma unroll
        for (int nt = 0; nt < 4; ++nt) {
            int col = wn * 64 + nt * 16 + q;
            #pragma unroll
            for (int r = 0; r < 4; ++r) {
                int rl = 4 * g + r;
                obuf[rl][col] = sigmoid_f(acc[p][nt][r] + bn[nt]);
            }
        }
        __syncthreads();
        {
            int rl = t >> 4, c16 = t & 15;
            int grow = m0 + p * 16 + rl;
            if (grow < M) {
                float* orow = out + (size_t)grow * 256 + c16 * 16;
                #pragma unroll
                for (int i = 0; i < 4; ++i) {
                    float4 g4 = *reinterpret_cast<const float4*>(&obuf[rl][c16 * 16 + i * 4]);
                    float4 a4 = *reinterpret_cast<const float4*>(orow + i * 4);
                    a4.x *= g4.x; a4.y *= g4.y; a4.z *= g4.z; a4.w *= g4.w;
                    *reinterpret_cast<float4*>(orow + i * 4) = a4;
                }
            }
        }
        __syncthreads();
    }
}

// ---------------------------------------------------------------------------
// D+E fused (R11-exact, measured best): Wf = (silu(A@wf2+b2))@wf3+b3.
// dbuf staging 16 KB + 32 KB f2l, launch_bounds(256,3).
// ---------------------------------------------------------------------------
__global__ __launch_bounds__(256, 3)
void fused_de_kernel(const ushort_t* A, const ushort_t* __restrict__ Wt2,
                     const float* __restrict__ b2,
                     const ushort_t* __restrict__ Wt3, const float* __restrict__ b3,
                     ushort_t* out, int M)
{
    __shared__ __align__(16) unsigned char sbuf[2][8192];
    __shared__ __align__(16) unsigned char f2l[64 * 512];

    const int t  = threadIdx.x;
    const int m0 = blockIdx.x * 64;
    const int wn   = t >> 6;
    const int lane = t & 63;
    const int g = lane >> 4, q = lane & 15;

    const int s0r = t >> 3,         s0u = t & 7;
    const int s1r = (t + 256) >> 3, s1u = t & 7;
    const ushort_t* src0base = A + (size_t)((m0 + s0r < M) ? (m0 + s0r) : (M - 1)) * 256 + ((s0u ^ (s0r & 7)) * 8);
    const ushort_t* src1base = A + (size_t)((m0 + s1r < M) ? (m0 + s1r) : (M - 1)) * 256 + ((s1u ^ (s1r & 7)) * 8);

    uint4 p0 = *reinterpret_cast<const uint4*>(src0base);
    uint4 p1 = *reinterpret_cast<const uint4*>(src1base);
    *reinterpret_cast<uint4*>(&sbuf[0][t * 16])         = p0;
    *reinterpret_cast<uint4*>(&sbuf[0][(t + 256) * 16]) = p1;
    __syncthreads();

    f32x4 acc[4][4];
    #pragma unroll
    for (int mt = 0; mt < 4; ++mt)
        #pragma unroll
        for (int nt = 0; nt < 4; ++nt) acc[mt][nt] = (f32x4){0.f, 0.f, 0.f, 0.f};

    for (int kt = 0; kt < 4; ++kt) {
        const int cur = kt & 1;
        uint4 nx0, nx1;
        if (kt < 3) {
            nx0 = *reinterpret_cast<const uint4*>(src0base + (kt + 1) * 64);
            nx1 = *reinterpret_cast<const uint4*>(src1base + (kt + 1) * 64);
        }
        #pragma unroll
        for (int ks = 0; ks < 2; ++ks) {
            bf16x8 b[4];
            #pragma unroll
            for (int nt = 0; nt < 4; ++nt) {
                int n = wn * 64 + nt * 16 + q;
                b[nt] = *reinterpret_cast<const bf16x8*>(Wt2 + (size_t)n * 256 + kt * 64 + ks * 32 + g * 8);
            }
            bf16x8 a[4];
            #pragma unroll
            for (int mt = 0; mt < 4; ++mt) {
                int r = mt * 16 + q;
                int u = (ks * 4 + g) ^ (r & 7);
                a[mt] = *reinterpret_cast<const bf16x8*>(&sbuf[cur][r * 128 + u * 16]);
            }
            #pragma unroll
            for (int mt = 0; mt < 4; ++mt)
                #pragma unroll
                for (int nt = 0; nt < 4; ++nt)
                    acc[mt][nt] = __builtin_amdgcn_mfma_f32_16x16x32_bf16(a[mt], b[nt], acc[mt][nt], 0, 0, 0);
        }
        __syncthreads();
        if (kt < 3) {
            *reinterpret_cast<uint4*>(&sbuf[cur ^ 1][t * 16])         = nx0;
            *reinterpret_cast<uint4*>(&sbuf[cur ^ 1][(t + 256) * 16]) = nx1;
            __syncthreads();
        }
    }

    const bool evenq = (q & 1) == 0;
    #pragma unroll
    for (int nt = 0; nt < 4; ++nt) {
        int n0  = wn * 64 + nt * 16 + q;
        int n_e = n0 & ~1;
        float2 bv = *reinterpret_cast<const float2*>(b2 + n_e);
        #pragma unroll
        for (int mt = 0; mt < 4; ++mt) {
            float v[4], p[4];
            #pragma unroll
            for (int r = 0; r < 4; ++r) { v[r] = acc[mt][nt][r]; p[r] = __shfl_xor(v[r], 1, 64); }
            #pragma unroll
            for (int rr = 0; rr < 2; ++rr) {
                int r = evenq ? rr : (2 + rr);
                float lo = silu_f((evenq ? v[r] : p[r]) + bv.x);
                float hi = silu_f((evenq ? p[r] : v[r]) + bv.y);
                int m = mt * 16 + 4 * g + r;
                unsigned u = (unsigned)f2bf(lo) | ((unsigned)f2bf(hi) << 16);
                int byte = m * 512 + (((n_e >> 3) ^ (m & 7)) << 4) + ((n_e & 7) * 2);
                *reinterpret_cast<unsigned*>(f2l + byte) = u;
            }
        }
    }
    __syncthreads();

    #pragma unroll
    for (int mt = 0; mt < 4; ++mt)
        #pragma unroll
        for (int nt = 0; nt < 4; ++nt) acc[mt][nt] = (f32x4){0.f, 0.f, 0.f, 0.f};

    #pragma unroll
    for (int kk = 0; kk < 8; ++kk) {
        bf16x8 b[4];
        #pragma unroll
        for (int nt = 0; nt < 4; ++nt) {
            int n = wn * 64 + nt * 16 + q;
            b[nt] = *reinterpret_cast<const bf16x8*>(Wt3 + (size_t)n * 256 + kk * 32 + g * 8);
        }
        bf16x8 a[4];
        #pragma unroll
        for (int mt = 0; mt < 4; ++mt) {
            int m = mt * 16 + q;
            int unit = (4 * kk + g) ^ (m & 7);
            a[mt] = *reinterpret_cast<const bf16x8*>(f2l + m * 512 + unit * 16);
        }
        #pragma unroll
        for (int mt = 0; mt < 4; ++mt)
            #pragma unroll
            for (int nt = 0; nt < 4; ++nt)
                acc[mt][nt] = __builtin_amdgcn_mfma_f32_16x16x32_bf16(a[mt], b[nt], acc[mt][nt], 0, 0, 0);
    }

    unsigned char* obuf = &sbuf[0][0];
    #pragma unroll
    for (int half = 0; half < 2; ++half) {
        __syncthreads();
        #pragma unroll
        for (int mtl = 0; mtl < 2; ++mtl) {
            int mt = half * 2 + mtl;
            #pragma unroll
            for (int nt = 0; nt < 4; ++nt) {
                int n0  = wn * 64 + nt * 16 + q;
                int n_e = n0 & ~1;
                float2 bv = *reinterpret_cast<const float2*>(b3 + n_e);
                float v[4], p[4];
                #pragma unroll
                for (int r = 0; r < 4; ++r) { v[r] = acc[mt][nt][r]; p[r] = __shfl_xor(v[r], 1, 64); }
                #pragma unroll
                for (int rr = 0; rr < 2; ++rr) {
                    int r = evenq ? rr : (2 + rr);
                    float lo = (evenq ? v[r] : p[r]) + bv.x;
                    float hi = (evenq ? p[r] : v[r]) + bv.y;
                    int ml = mtl * 16 + 4 * g + r;
                    unsigned u = (unsigned)f2bf(lo) | ((unsigned)f2bf(hi) << 16);
                    *reinterpret_cast<unsigned*>(obuf + ml * 512 + n_e * 2) = u;
                }
            }
        }
        __syncthreads();
        {
            int row = t >> 3, c = t & 7;
            int grow = m0 + half * 32 + row;
            if (grow < M) {
                #pragma unroll
                for (int i = 0; i < 4; ++i) {
                    uint4 v = *reinterpret_cast<const uint4*>(obuf + row * 512 + (c + 8 * i) * 16);
                    *reinterpret_cast<uint4*>(out + (size_t)grow * 256 + (c + 8 * i) * 8) = v;
                }
            }
        }
    }
}

// ---------------------------------------------------------------------------
// F (single-chunk): fused agg + residual + LN.
// Wave per node: h = x[n] + sum_s Wf[s]*y[col[s]]; out0 = LN(h)*g+b; bf16 copy.
// Handles empty nodes (h = x row).  Requires ALL slots in range (cs=0,ce=E).
// ---------------------------------------------------------------------------
__global__ __launch_bounds__(256)
void agg_ln_node_kernel(const ushort_t* __restrict__ Wf, const int* __restrict__ colp,
                        const int* __restrict__ start, const ushort_t* __restrict__ y,
                        const float* __restrict__ x,
                        const float* __restrict__ gg, const float* __restrict__ bb,
                        float* __restrict__ out0, ushort_t* __restrict__ out_bf, int N)
{
    int lane = threadIdx.x & 63;
    int n    = blockIdx.x * 4 + (threadIdx.x >> 6);
    if (n >= N) return;
    int s0 = start[n], s1 = start[n + 1];

    float4 hx = reinterpret_cast<const float4*>(x)[n * 64 + lane];
    float h0 = hx.x, h1 = hx.y, h2 = hx.z, h3 = hx.w;
    for (int s = s0; s < s1; ++s) {
        uint2 wv = *reinterpret_cast<const uint2*>(Wf + (size_t)s * 256 + lane * 4);
        int c = colp[s];
        uint2 yv = *reinterpret_cast<const uint2*>(y + (size_t)c * 256 + lane * 4);
        h0 += bf2f((ushort_t)(wv.x & 0xffff)) * bf2f((ushort_t)(yv.x & 0xffff));
        h1 += bf2f((ushort_t)(wv.x >> 16))    * bf2f((ushort_t)(yv.x >> 16));
        h2 += bf2f((ushort_t)(wv.y & 0xffff)) * bf2f((ushort_t)(yv.y & 0xffff));
        h3 += bf2f((ushort_t)(wv.y >> 16))    * bf2f((ushort_t)(yv.y >> 16));
    }

    float su = h0 + h1 + h2 + h3;
    float s2 = h0 * h0 + h1 * h1 + h2 * h2 + h3 * h3;
    #pragma unroll
    for (int off = 32; off > 0; off >>= 1) {
        su += __shfl_xor(su, off, 64);
        s2 += __shfl_xor(s2, off, 64);
    }
    float mu  = su * (1.0f / 256.0f);
    float var = s2 * (1.0f / 256.0f) - mu * mu;
    float inv = rsqrtf(var + F_EPS_LN);
    float4 gv = reinterpret_cast<const float4*>(gg)[lane];
    float4 bv = reinterpret_cast<const float4*>(bb)[lane];
    float4 o;
    o.x = (h0 - mu) * inv * gv.x + bv.x;
    o.y = (h1 - mu) * inv * gv.y + bv.y;
    o.z = (h2 - mu) * inv * gv.z + bv.z;
    o.w = (h3 - mu) * inv * gv.w + bv.w;
    reinterpret_cast<float4*>(out0)[n * 64 + lane] = o;
    ushort_t ob[4] = {f2bf(o.x), f2bf(o.y), f2bf(o.z), f2bf(o.w)};
    *reinterpret_cast<uint2*>(out_bf + (size_t)n * 256 + lane * 4) = *reinterpret_cast<uint2*>(ob);
}

// ---------------------------------------------------------------------------
// F (multi-chunk): agg per node into pre-zeroed agg buffer.
// ---------------------------------------------------------------------------
__global__ __launch_bounds__(256)
void agg_node_kernel(const ushort_t* __restrict__ Wf, const int* __restrict__ colp,
                     const int* __restrict__ start, const ushort_t* __restrict__ y,
                     float* __restrict__ agg, int cs, int ce, int N)
{
    int lane = threadIdx.x & 63;
    int n    = blockIdx.x * 4 + (threadIdx.x >> 6);
    if (n >= N) return;
    int s0 = start[n], s1 = start[n + 1];
    if (s1 <= cs || s0 >= ce) return;
    int lo = (s0 > cs) ? s0 : cs;
    int hi = (s1 < ce) ? s1 : ce;

    float h0 = 0.f, h1 = 0.f, h2 = 0.f, h3 = 0.f;
    for (int s = lo; s < hi; ++s) {
        uint2 wv = *reinterpret_cast<const uint2*>(Wf + (size_t)(s - cs) * 256 + lane * 4);
        int c = colp[s];
        uint2 yv = *reinterpret_cast<const uint2*>(y + (size_t)c * 256 + lane * 4);
        h0 += bf2f((ushort_t)(wv.x & 0xffff)) * bf2f((ushort_t)(yv.x & 0xffff));
        h1 += bf2f((ushort_t)(wv.x >> 16))    * bf2f((ushort_t)(yv.x >> 16));
        h2 += bf2f((ushort_t)(wv.y & 0xffff)) * bf2f((ushort_t)(yv.y & 0xffff));
        h3 += bf2f((ushort_t)(wv.y >> 16))    * bf2f((ushort_t)(yv.y >> 16));
    }

    float* row = agg + (size_t)n * 256 + lane * 4;
    if (s0 >= cs && s1 <= ce) {
        *reinterpret_cast<float4*>(row) = make_float4(h0, h1, h2, h3);
    } else {
        unsafeAtomicAdd(&row[0], h0);
        unsafeAtomicAdd(&row[1], h1);
        unsafeAtomicAdd(&row[2], h2);
        unsafeAtomicAdd(&row[3], h3);
    }
}

// ---------------------------------------------------------------------------
// Fallback (ws too small): R7 fused CSR kernel.
// ---------------------------------------------------------------------------
template<int KS, int NT, bool SILU>
__device__ __forceinline__ void mlp_stage(const unsigned char* in, unsigned char* out,
                                          const ushort_t* __restrict__ Wt,
                                          const float* __restrict__ bias,
                                          int wn, int g, int q)
{
    constexpr int K = KS * 32;
    f32x4 acc[2][NT];
    #pragma unroll
    for (int mt = 0; mt < 2; ++mt)
        #pragma unroll
        for (int nt = 0; nt < NT; ++nt) acc[mt][nt] = (f32x4){0.f, 0.f, 0.f, 0.f};

    #pragma unroll
    for (int kk = 0; kk < KS; ++kk) {
        bf16x8 b[NT];
        #pragma unroll
        for (int nt = 0; nt < NT; ++nt) {
            int n = (wn * NT + nt) * 16 + q;
            b[nt] = *reinterpret_cast<const bf16x8*>(Wt + n * K + kk * 32 + g * 8);
        }
        bf16x8 a[2];
        #pragma unroll
        for (int mt = 0; mt < 2; ++mt) {
            int m = mt * 16 + q;
            int unit = (4 * kk + g) ^ (m & 7);
            a[mt] = *reinterpret_cast<const bf16x8*>(in + m * 512 + unit * 16);
        }
        #pragma unroll
        for (int mt = 0; mt < 2; ++mt)
            #pragma unroll
            for (int nt = 0; nt < NT; ++nt)
                acc[mt][nt] = __builtin_amdgcn_mfma_f32_16x16x32_bf16(a[mt], b[nt], acc[mt][nt], 0, 0, 0);
    }

    const bool evenq = (q & 1) == 0;
    #pragma unroll
    for (int nt = 0; nt < NT; ++nt) {
        int n0  = (wn * NT + nt) * 16 + q;
        int n_e = n0 & ~1;
        float2 bv = *reinterpret_cast<const float2*>(bias + n_e);
        #pragma unroll
        for (int mt = 0; mt < 2; ++mt) {
            float v[4], p[4];
            #pragma unroll
            for (int r = 0; r < 4; ++r) { v[r] = acc[mt][nt][r]; p[r] = __shfl_xor(v[r], 1, 64); }
            #pragma unroll
            for (int rr = 0; rr < 2; ++rr) {
                int r = evenq ? rr : (2 + rr);
                float lo = (evenq ? v[r] : p[r]) + bv.x;
                float hi = (evenq ? p[r] : v[r]) + bv.y;
                if (SILU) { lo = silu_f(lo); hi = silu_f(hi); }
                int m = mt * 16 + 4 * g + r;
                unsigned u = (unsigned)f2bf(lo) | ((unsigned)f2bf(hi) << 16);
                int byte = m * 512 + (((n_e >> 3) ^ (m & 7)) << 4) + ((n_e & 7) * 2);
                *reinterpret_cast<unsigned*>(out + byte) = u;
            }
        }
    }
}

__global__ __launch_bounds__(256, 4)
void edge_csr_kernel(const float* __restrict__ distp, const int* __restrict__ colp,
                     const int* __restrict__ nodep, const int* __restrict__ start,
                     const float* __restrict__ centers, const float* __restrict__ widths,
                     const ushort_t* __restrict__ wt_rbf1, const float* __restrict__ rbf_b1,
                     const ushort_t* __restrict__ wt_comb, const float* __restrict__ b_comb,
                     const ushort_t* __restrict__ wt_f2, const float* __restrict__ filt_b2,
                     const ushort_t* __restrict__ wt_f3, const float* __restrict__ filt_b3,
                     const ushort_t* __restrict__ y, float* __restrict__ agg, int E)
{
    __shared__ __align__(16) unsigned char buf[32768];
    __shared__ int node_s[32];
    __shared__ int flag_s[32];
    unsigned char* bufA = buf;
    unsigned char* bufB = buf + 16384;

    const int t  = threadIdx.x;
    const int e0 = blockIdx.x * 32;
    const int wn   = t >> 6;
    const int lane = t & 63;
    const int g = lane >> 4, q = lane & 15;

    if (t < 32) {
        int ge = e0 + t;
        int nd = (ge < E) ? nodep[ge] : -1;
        node_s[t] = nd;
        int fl = 0;
        if (nd >= 0) {
            int lo = start[nd], hi = start[nd + 1];
            fl = (lo >= e0 && hi <= e0 + 32) ? 1 : 0;
        }
        flag_s[t] = fl;
    }

    const int e_own  = t >> 3;
    const int chunk  = t & 7;
    const int ge_own = e0 + e_own;
    const int col_own = (ge_own < E) ? colp[ge_own] : 0;
    uint4 yv[4];
    #pragma unroll
    for (int i = 0; i < 4; ++i)
        yv[i] = *reinterpret_cast<const uint4*>(y + (size_t)col_own * 256 + (i * 8 + chunk) * 8);

    {
        float d = (ge_own < E) ? distp[ge_own] : F_CUTOFF;
        float env = (d < F_CUTOFF) ? 0.5f * (__cosf(d * (F_PI / F_CUTOFF)) + 1.0f) : 0.0f;
        unsigned char* rowp = bufA + e_own * 512;
        int k0 = chunk * 8;
        #pragma unroll
        for (int i = 0; i < 4; ++i) {
            int n = k0 + 2 * i;
            float c0 = centers[n],     w0 = fabsf(widths[n]) + F_EPS_W;
            float c1 = centers[n + 1], w1 = fabsf(widths[n + 1]) + F_EPS_W;
            float z0 = (d - c0) / w0, z1 = (d - c1) / w1;
            float r0 = env * __expf(-0.5f * z0 * z0);
            float r1 = env * __expf(-0.5f * z1 * z1);
            unsigned u = (unsigned)f2bf(r0) | ((unsigned)f2bf(r1) << 16);
            int byte = (((n >> 3) ^ (e_own & 7)) << 4) + ((n & 7) * 2);
            *reinterpret_cast<unsigned*>(rowp + byte) = u;
        }
    }
    __syncthreads();

    mlp_stage<2, 1, true>(bufA, bufB, wt_rbf1, rbf_b1, wn, g, q);
    __syncthreads();
    mlp_stage<2, 4, true>(bufB, bufA, wt_comb, b_comb, wn, g, q);
    __syncthreads();
    mlp_stage<8, 4, true>(bufA, bufB, wt_f2, filt_b2, wn, g, q);
    __syncthreads();

    #pragma unroll
    for (int i = 0; i < 4; ++i)
        *reinterpret_cast<uint4*>(bufA + e_own * 512 + (i * 8 + chunk) * 16) = yv[i];
    __syncthreads();

    f32x4 acc[2][4];
    #pragma unroll
    for (int mt = 0; mt < 2; ++mt)
        #pragma unroll
        for (int nt = 0; nt < 4; ++nt) acc[mt][nt] = (f32x4){0.f, 0.f, 0.f, 0.f};

    #pragma unroll
    for (int kk = 0; kk < 8; ++kk) {
        bf16x8 b[4];
        #pragma unroll
        for (int nt = 0; nt < 4; ++nt) {
            int n = (wn * 4 + nt) * 16 + q;
            b[nt] = *reinterpret_cast<const bf16x8*>(wt_f3 + n * 256 + kk * 32 + g * 8);
        }
        bf16x8 a[2];
        #pragma unroll
        for (int mt = 0; mt < 2; ++mt) {
            int m = mt * 16 + q;
            int unit = (4 * kk + g) ^ (m & 7);
            a[mt] = *reinterpret_cast<const bf16x8*>(bufB + m * 512 + unit * 16);
        }
        #pragma unroll
        for (int mt = 0; mt < 2; ++mt)
            #pragma unroll
            for (int nt = 0; nt < 4; ++nt)
                acc[mt][nt] = __builtin_amdgcn_mfma_f32_16x16x32_bf16(a[mt], b[nt], acc[mt][nt], 0, 0, 0);
    }

    float bn[4];
    int   nn[4];
    #pragma unroll
    for (int nt = 0; nt < 4; ++nt) { nn[nt] = (wn * 4 + nt) * 16 + q; bn[nt] = filt_b3[nn[nt]]; }

    #pragma unroll
    for (int mt = 0; mt < 2; ++mt) {
        #pragma unroll
        for (int r = 0; r < 4; ++r) {
            int m = mt * 16 + 4 * g + r;
            const unsigned char* yrow = bufA + m * 512;
            #pragma unroll
            for (int nt = 0; nt < 4; ++nt) {
                float yvv = bf2f(*reinterpret_cast<const ushort_t*>(yrow + nn[nt] * 2));
                acc[mt][nt][r] = (acc[mt][nt][r] + bn[nt]) * yvv;
            }
        }
    }
    __syncthreads();

    float* msgf = reinterpret_cast<float*>(buf);
    #pragma unroll
    for (int mt = 0; mt < 2; ++mt) {
        #pragma unroll
        for (int r = 0; r < 4; ++r) {
            int m = mt * 16 + 4 * g + r;
            #pragma unroll
            for (int nt = 0; nt < 4; ++nt)
                msgf[m * 256 + nn[nt]] = acc[mt][nt][r];
        }
    }
    __syncthreads();

    {
        const int j = t;
        float accv = 0.f;
        int cur = -2, rs = 0;
        #pragma unroll 4
        for (int r = 0; r < 32; ++r) {
            int nd = node_s[r];
            if (nd != cur) {
                if (cur >= 0) {
                    if (flag_s[rs]) agg[(size_t)cur * 256 + j] = accv;
                    else            unsafeAtomicAdd(&agg[(size_t)cur * 256 + j], accv);
                }
                cur = nd; rs = r; accv = msgf[r * 256 + j];
            } else {
                accv += msgf[r * 256 + j];
            }
        }
        if (cur >= 0) {
            if (flag_s[rs]) agg[(size_t)cur * 256 + j] = accv;
            else            unsafeAtomicAdd(&agg[(size_t)cur * 256 + j], accv);
        }
    }
}

// ---------------------------------------------------------------------------
// LN in-place: d_out = LN(x + d_out) * g + b; also emits bf16 copy.
// ---------------------------------------------------------------------------
__global__ __launch_bounds__(256)
void ln_kernel(const float* __restrict__ x, const float* __restrict__ agg,
               const float* __restrict__ g, const float* __restrict__ b,
               float* __restrict__ out0, ushort_t* __restrict__ out_bf, int N)
{
    int lane = threadIdx.x & 63;
    int row  = blockIdx.x * 4 + (threadIdx.x >> 6);
    if (row >= N) return;
    float4 hx = reinterpret_cast<const float4*>(x)[row * 64 + lane];
    float4 ha = reinterpret_cast<const float4*>(agg)[row * 64 + lane];
    float4 h  = make_float4(hx.x + ha.x, hx.y + ha.y, hx.z + ha.z, hx.w + ha.w);
    float s  = h.x + h.y + h.z + h.w;
    float s2 = h.x * h.x + h.y * h.y + h.z * h.z + h.w * h.w;
    #pragma unroll
    for (int off = 32; off > 0; off >>= 1) {
        s  += __shfl_xor(s,  off, 64);
        s2 += __shfl_xor(s2, off, 64);
    }
    float mu  = s * (1.0f / 256.0f);
    float var = s2 * (1.0f / 256.0f) - mu * mu;
    float inv = rsqrtf(var + F_EPS_LN);
    float4 gv = reinterpret_cast<const float4*>(g)[lane];
    float4 bv = reinterpret_cast<const float4*>(b)[lane];
    float4 o;
    o.x = (h.x - mu) * inv * gv.x + bv.x;
    o.y = (h.y - mu) * inv * gv.y + bv.y;
    o.z = (h.z - mu) * inv * gv.z + bv.z;
    o.w = (h.w - mu) * inv * gv.w + bv.w;
    reinterpret_cast<float4*>(out0)[row * 64 + lane] = o;
    ushort_t ob[4] = {f2bf(o.x), f2bf(o.y), f2bf(o.z), f2bf(o.w)};
    *reinterpret_cast<uint2*>(out_bf + (size_t)row * 256 + lane * 4) = *reinterpret_cast<uint2*>(ob);
}

// ---------------------------------------------------------------------------
extern "C" void kernel_launch(void* const* d_in, const int* in_sizes, int n_in,
                              void* d_out, int out_size, void* d_ws, size_t ws_size,
                              hipStream_t stream)
{
    const float* x       = (const float*)d_in[0];
    const int*   eidx    = (const int*)  d_in[1];
    const float* dist    = (const float*)d_in[2];
    const float* centers = (const float*)d_in[3];
    const float* widths  = (const float*)d_in[4];
    const float* rbf_w1  = (const float*)d_in[5];
    const float* rbf_b1  = (const float*)d_in[6];
    const float* rbf_w2  = (const float*)d_in[7];
    const float* rbf_b2  = (const float*)d_in[8];
    const float* filt_w1 = (const float*)d_in[9];
    const float* filt_b1 = (const float*)d_in[10];
    const float* filt_w2 = (const float*)d_in[11];
    const float* filt_b2 = (const float*)d_in[12];
    const float* filt_w3 = (const float*)d_in[13];
    const float* filt_b3 = (const float*)d_in[14];
    const float* node_w  = (const float*)d_in[15];
    const float* node_b  = (const float*)d_in[16];
    const float* ln_g    = (const float*)d_in[17];
    const float* ln_b    = (const float*)d_in[18];
    const float* gate_w  = (const float*)d_in[19];
    const float* gate_b  = (const float*)d_in[20];

    const int N = in_sizes[0] / 256;
    const int E = in_sizes[2];

    char* wsb = (char*)d_ws;
    size_t off = 0;
    auto alloc = [&](size_t bytes, size_t align) -> char* {
        off = (off + align - 1) & ~(align - 1);
        char* p = wsb + off;
        off += bytes;
        return p;
    };
    ushort_t* y_bf   = (ushort_t*)alloc((size_t)N * 256 * 2, 16);
    ushort_t* wt1    = (ushort_t*)alloc(64 * 64 * 2, 16);
    ushort_t* wcomb  = (ushort_t*)alloc(256 * 64 * 2, 16);
    ushort_t* wf2t   = (ushort_t*)alloc(256 * 256 * 2, 16);
    ushort_t* wf3t   = (ushort_t*)alloc(256 * 256 * 2, 16);
    ushort_t* wnodet = (ushort_t*)alloc(256 * 256 * 2, 16);
    ushort_t* wgatet = (ushort_t*)alloc(256 * 256 * 2, 16);
    float*    bcomb  = (float*)   alloc(256 * 4, 16);
    int*      part   = (int*)     alloc(256 * 4, 16);
    int*      cnt    = (int*)     alloc((size_t)N * 4, 16);
    int*      start  = (int*)     alloc(((size_t)N + 1) * 4, 16);
    int*      colp   = (int*)     alloc((size_t)E * 4, 16);
    int*      nodep  = (int*)     alloc((size_t)E * 4, 16);
    float*    distp  = (float*)   alloc((size_t)E * 4, 256);

    size_t fixed_off = (off + 1023) & ~(size_t)1023;
    size_t avail = (ws_size > fixed_off) ? (ws_size - fixed_off) : 0;
    long Rl = (long)(avail / 640);
    int R = (int)(Rl & ~127L);
    int Eround = (E + 127) & ~127;
    if (R > Eround) R = Eround;
    const bool dense = (R >= 128) && ((E + R - 1) / R <= 8)
                       && ((size_t)R * 640 >= (size_t)N * 512 + 1024);
    const int nchunks = dense ? ((E + R - 1) / R) : 0;
    ushort_t* rt_buf = (ushort_t*)(wsb + fixed_off);
    ushort_t* fw_buf = rt_buf + (size_t)R * 64;
    ushort_t* x_bf   = rt_buf;   // alias: used only before chunk loop
    ushort_t* a_bf   = rt_buf;   // alias: used only after chunk loop

    dim3 b256(256);
    const int range = (N + 255) / 256;

    // weight prep
    cvt_transpose_kernel<<<dim3((64 * 64 + 255) / 256),   b256, 0, stream>>>(rbf_w1,  wt1, 64, 64, 6);
    combine_w_kernel<<<dim3(64), b256, 0, stream>>>(rbf_w2, filt_w1, wcomb);
    combine_b_kernel<<<dim3(1), b256, 0, stream>>>(rbf_b2, filt_w1, filt_b1, bcomb);
    cvt_transpose_kernel<<<dim3((256 * 256 + 255) / 256), b256, 0, stream>>>(filt_w2, wf2t, 256, 256, 8);
    cvt_transpose_kernel<<<dim3((256 * 256 + 255) / 256), b256, 0, stream>>>(filt_w3, wf3t, 256, 256, 8);
    cvt_transpose_kernel<<<dim3((256 * 256 + 255) / 256), b256, 0, stream>>>(node_w,  wnodet, 256, 256, 8);
    cvt_transpose_kernel<<<dim3((256 * 256 + 255) / 256), b256, 0, stream>>>(gate_w,  wgatet, 256, 256, 8);

    hipMemsetAsync(cnt, 0, (size_t)N * 4, stream);

    if (dense) {
        cast_bf16_kernel<<<dim3((N * 64 + 255) / 256), b256, 0, stream>>>(x, x_bf, (long)N * 64);
        gemm_k256_kernel<false><<<dim3((N + 63) / 64), b256, 0, stream>>>(
            x_bf, wnodet, node_b, y_bf, N);
    } else {
        gemm256_bf16_kernel<<<dim3((N + 63) / 64), b256, 0, stream>>>(x, node_w, node_b, y_bf, N);
    }

    // CSR build
    count_kernel<<<dim3((E + 255) / 256), b256, 0, stream>>>(eidx, cnt, E);
    scan_sum_kernel<<<dim3(256), b256, 0, stream>>>(cnt, part, N, range);
    scan_write_kernel<<<dim3(1), b256, 0, stream>>>(part, cnt, start, N, range, E);
    scatter_kernel<<<dim3((E + 255) / 256), b256, 0, stream>>>(eidx, dist, cnt, colp, nodep, distp, E);

    if (dense) {
        if (nchunks > 1)
            hipMemsetAsync(d_out, 0, (size_t)out_size * sizeof(float), stream);

        for (int cs = 0; cs < E; cs += R) {
            int Mc = (E - cs < R) ? (E - cs) : R;
            rbf_t1_kernel<<<dim3((Mc + 127) / 128), b256, 0, stream>>>(
                distp + cs, centers, widths, wt1, rbf_b1, rt_buf, Mc);
            gemm_k64n256_kernel<<<dim3((Mc + 63) / 64), b256, 0, stream>>>(
                rt_buf, wcomb, bcomb, fw_buf, Mc);
            fused_de_kernel<<<dim3((Mc + 63) / 64), b256, 0, stream>>>(
                fw_buf, wf2t, filt_b2, wf3t, filt_b3, fw_buf, Mc);
            if (nchunks == 1) {
                agg_ln_node_kernel<<<dim3((N + 3) / 4), b256, 0, stream>>>(
                    fw_buf, colp, start, y_bf, x, ln_g, ln_b, (float*)d_out, a_bf, N);
            } else {
                agg_node_kernel<<<dim3((N + 3) / 4), b256, 0, stream>>>(
                    fw_buf, colp, start, y_bf, (float*)d_out, cs, cs + Mc, N);
            }
        }
        if (nchunks > 1) {
            ln_kernel<<<dim3((N + 3) / 4), b256, 0, stream>>>(
                x, (float*)d_out, ln_g, ln_b, (float*)d_out, a_bf, N);
        }
        gate_mfma_kernel<<<dim3((N + 63) / 64), b256, 0, stream>>>(
            a_bf, wgatet, gate_b, (float*)d_out, N);
    } else {
        hipMemsetAsync(d_out, 0, (size_t)out_size * sizeof(float), stream);
        edge_csr_kernel<<<dim3((E + 31) / 32), b256, 0, stream>>>(
            distp, colp, nodep, start, centers, widths,
            wt1, rbf_b1, wcomb, bcomb,
            wf2t, filt_b2, wf3t, filt_b3,
            y_bf, (float*)d_out, E);
        ln_kernel<<<dim3((N + 3) / 4), b256, 0, stream>>>(
            x, (float*)d_out, ln_g, ln_b, (float*)d_out, y_bf, N);
        gate_gemm_kernel<<<dim3((N + 63) / 64), b256, 0, stream>>>(
            (float*)d_out, gate_w, gate_b, (float*)d_out, N);
    }
}